// Round 7
// baseline (1450.447 us; speedup 1.0000x reference)
//
#include <hip/hip_runtime.h>

typedef unsigned short u16;
typedef unsigned int   u32;
typedef short   short8  __attribute__((ext_vector_type(8)));
typedef float   floatx4 __attribute__((ext_vector_type(4)));

#define NTOK 8192
#define SEQ  512
#define NLAYER 6

// ---- workspace layout (bytes) ----
#define OFF_WT   ((size_t)0)          // transposed weights (bf16), 19,005,440 u16
#define OFF_HF   ((size_t)38010880)   // h fp32   [8192][512]
#define OFF_HB   ((size_t)54788096)   // h bf16   [8192][512]
#define OFF_QKV  ((size_t)63176704)   // qkv bf16 [8192][1536] (25.2 MB)
#define OFF_CTX  ((size_t)88342528)   // ctx bf16 [8192][512]
#define OFF_GOUT ((size_t)96731136)   // gout0 fp32 [8192][512]
#define OFF_FF   ((size_t)113508352)  // ff bf16  [8192][2048]  (33.5 MB)
#define OFF_HD1  ((size_t)147062784)  // head1 bf16 [8192][256] (4.2 MB)
// aliases:
//   gout1 (split-K partial, f32 [8192][512]) -> qkv region (dead during Wo/FFN2)
//   vT bf16 [128 bh][64][512] (8.4 MB) -> ff region (dead during attn)
//   relB_all bf16 [6][272][64] (209 KB) -> hd1 region (hd1 written only at end)
#define OFF_VT   OFF_FF
#define OFF_RELB OFF_HD1

#define LSTRIDE 3145728   // wT elems per layer: [QT;KT;VT](1536x512), WoT, w1T(2048x512), w2T(512x2048)
#define P1T_OFF 18874368  // p1T [256][512]

__device__ __forceinline__ float b2f(u16 v) { return __uint_as_float(((u32)v) << 16); }
__device__ __forceinline__ float lo16(u32 v) { return __uint_as_float(v << 16); }
__device__ __forceinline__ float hi16(u32 v) { return __uint_as_float(v & 0xffff0000u); }
__device__ __forceinline__ u16 f2b(float f) {
  u32 x = __float_as_uint(f);
  return (u16)((x + 0x7fffu + ((x >> 16) & 1u)) >> 16);
}
__device__ __forceinline__ u32 pack2(float a, float b) {
  return (u32)f2b(a) | ((u32)f2b(b) << 16);
}

typedef __attribute__((address_space(1))) void* gas_t;
typedef __attribute__((address_space(3))) void* las_t;

// ---------------------------------------------------------------------------
// Transpose all f32 weight matrices into wT (bf16 [N][K] for gemm_bt).
// ---------------------------------------------------------------------------
__global__ __launch_bounds__(256) void transpose_all(
    const float* __restrict__ Wq, const float* __restrict__ Wk,
    const float* __restrict__ Wv, const float* __restrict__ Wo,
    const float* __restrict__ w1, const float* __restrict__ w2,
    const float* __restrict__ p1, u16* __restrict__ wT)
{
  __shared__ u16 tile[64][65];
  const int tb = blockIdx.x;
  const float* src; u16* dst; int R, C, tidx;
  if (tb < 4608) {
    const int l = tb / 768, r = tb % 768;
    const size_t lofs = (size_t)l * LSTRIDE;
    if (r < 256) {
      const int m = r >> 6; tidx = r & 63; R = 512; C = 512;
      const float* bases[4] = {Wq, Wk, Wv, Wo};
      src = bases[m] + (size_t)l * 262144;
      dst = wT + lofs + (size_t)m * 262144;
    } else if (r < 512) {
      tidx = r - 256; R = 512; C = 2048;
      src = w1 + (size_t)l * 1048576; dst = wT + lofs + 1048576;
    } else {
      tidx = r - 512; R = 2048; C = 512;
      src = w2 + (size_t)l * 1048576; dst = wT + lofs + 2097152;
    }
  } else {
    tidx = tb - 4608; R = 512; C = 256;
    src = p1; dst = wT + P1T_OFF;
  }
  const int tcn = C >> 6;
  const int tr = tidx / tcn, tc = tidx % tcn;
  const int th = threadIdx.x;
  {
    const int lr = th >> 2, cg = (th & 3) * 16;
    const float* sp = src + (size_t)(tr*64 + lr) * C + tc*64 + cg;
    float4 f0 = *(const float4*)(sp);
    float4 f1 = *(const float4*)(sp + 4);
    float4 f2 = *(const float4*)(sp + 8);
    float4 f3 = *(const float4*)(sp + 12);
    u16* tp = &tile[lr][cg];
    tp[0]=f2b(f0.x); tp[1]=f2b(f0.y); tp[2]=f2b(f0.z); tp[3]=f2b(f0.w);
    tp[4]=f2b(f1.x); tp[5]=f2b(f1.y); tp[6]=f2b(f1.z); tp[7]=f2b(f1.w);
    tp[8]=f2b(f2.x); tp[9]=f2b(f2.y); tp[10]=f2b(f2.z); tp[11]=f2b(f2.w);
    tp[12]=f2b(f3.x); tp[13]=f2b(f3.y); tp[14]=f2b(f3.z); tp[15]=f2b(f3.w);
  }
  __syncthreads();
  {
    const int oc = th >> 2, rg = (th & 3) * 16;
    u32 wds[8];
    #pragma unroll
    for (int i = 0; i < 8; ++i)
      wds[i] = (u32)tile[rg + 2*i][oc] | ((u32)tile[rg + 2*i + 1][oc] << 16);
    u16* dp = dst + (size_t)(tc*64 + oc) * R + tr*64 + rg;
    uint4 o0; o0.x=wds[0]; o0.y=wds[1]; o0.z=wds[2]; o0.w=wds[3];
    uint4 o1; o1.x=wds[4]; o1.y=wds[5]; o1.z=wds[6]; o1.w=wds[7];
    *(uint4*)dp = o0;
    *(uint4*)(dp + 8) = o1;
  }
}

// ---------------------------------------------------------------------------
// h = x @ in_w + in_b + sinusoidal_pe   (K=50, exact f32)
// ---------------------------------------------------------------------------
__global__ __launch_bounds__(128) void input_proj(
    const float* __restrict__ x, const float* __restrict__ w, const float* __restrict__ ib,
    float* __restrict__ hf, u16* __restrict__ hb)
{
  const int row = blockIdx.x, t = threadIdx.x;
  const int s = row & (SEQ - 1);
  __shared__ float xs[50];
  if (t < 50) xs[t] = x[row*50 + t];
  __syncthreads();
  #pragma unroll
  for (int rep = 0; rep < 4; ++rep) {
    const int d = rep*128 + t;
    float acc = ib[d];
    #pragma unroll
    for (int i = 0; i < 50; ++i) acc += xs[i] * w[i*512 + d];
    const int ii = d >> 1;
    const float dv = __expf((float)(2*ii) * -0.017988946f); // -ln(10000)/512
    const float ang = (float)s * dv;
    const float pe = (d & 1) ? cosf(ang) : sinf(ang);
    const float v = acc + pe;
    hf[(size_t)row*512 + d] = v;
    hb[(size_t)row*512 + d] = f2b(v);
  }
}

// ---------------------------------------------------------------------------
// C[M][N] = A[M][K] @ Bt[N][K]^T over k in [z*kLen, (z+1)*kLen)
// BK=64: two m97-style 128x32 images per matrix, one barrier pair per 64 k.
// z = blockIdx.y. z==0 gets +bias; relu per flags bit1.
// flags bit2: blocks with n0>=1024 write V directly in vT-transposed layout.
// ---------------------------------------------------------------------------
__global__ __launch_bounds__(256) void gemm_bt(
    const u16* __restrict__ A, const u16* __restrict__ Bt,
    const float* __restrict__ bias,
    float* __restrict__ outF0, float* __restrict__ outF1, u16* __restrict__ outB,
    u16* __restrict__ vTout,
    const int M, const int N, const int K, const int kLen, const int flags)
{
  __shared__ __align__(16) u16 As[2*128*32];
  __shared__ __align__(16) u16 Bs[2*128*32];
  const int nb = N >> 7;
  const int bm = blockIdx.x / nb, bn = blockIdx.x % nb;
  const int z = blockIdx.y;
  const int kOff = z * kLen;
  const int m0 = bm << 7, n0 = bn << 7;
  const int tid = threadIdx.x;
  const int wave = tid >> 6, lane = tid & 63;
  const int wr = (wave >> 1) << 6, wc = (wave & 1) << 6;
  const int lrow = lane & 15, lquad = lane >> 4;

  floatx4 acc[4][4];
  #pragma unroll
  for (int i = 0; i < 4; ++i)
    #pragma unroll
    for (int j = 0; j < 4; ++j) { floatx4 zz = {0.f,0.f,0.f,0.f}; acc[i][j] = zz; }

  const u16* a0p = A  + (size_t)m0 * K + kOff;
  const u16* b0p = Bt + (size_t)n0 * K + kOff;
  const int c0 = tid, c1 = 256 + tid;
  const int ar0 = c0 >> 2, as0 = (c0 & 3) * 8;
  const int ar1 = c1 >> 2, as1 = (c1 & 3) * 8;

  for (int k0 = 0; k0 < kLen; k0 += 64) {
    #pragma unroll
    for (int hh = 0; hh < 2; ++hh) {
      const int kk = k0 + hh*32;
      __builtin_amdgcn_global_load_lds((gas_t)(a0p + (size_t)ar0*K + kk + as0), (las_t)(&As[hh*4096 + c0*8]), 16, 0, 0);
      __builtin_amdgcn_global_load_lds((gas_t)(a0p + (size_t)ar1*K + kk + as1), (las_t)(&As[hh*4096 + c1*8]), 16, 0, 0);
      __builtin_amdgcn_global_load_lds((gas_t)(b0p + (size_t)ar0*K + kk + as0), (las_t)(&Bs[hh*4096 + c0*8]), 16, 0, 0);
      __builtin_amdgcn_global_load_lds((gas_t)(b0p + (size_t)ar1*K + kk + as1), (las_t)(&Bs[hh*4096 + c1*8]), 16, 0, 0);
    }
    __syncthreads();
    #pragma unroll
    for (int hh = 0; hh < 2; ++hh) {
      short8 af[4], bf[4];
      #pragma unroll
      for (int i = 0; i < 4; ++i) af[i] = *(const short8*)&As[hh*4096 + (wr + i*16 + lrow)*32 + lquad*8];
      #pragma unroll
      for (int j = 0; j < 4; ++j) bf[j] = *(const short8*)&Bs[hh*4096 + (wc + j*16 + lrow)*32 + lquad*8];
      #pragma unroll
      for (int i = 0; i < 4; ++i)
        #pragma unroll
        for (int j = 0; j < 4; ++j)
          acc[i][j] = __builtin_amdgcn_mfma_f32_16x16x32_bf16(af[i], bf[j], acc[i][j], 0, 0, 0);
    }
    __syncthreads();
  }

  if ((flags & 4) && n0 >= 1024) {
    // V block of QKV: write directly into vT[(b*8+h)*64+d][s] (bf16)
    #pragma unroll
    for (int j = 0; j < 4; ++j) {
      const int cm = (n0 - 1024) + wc + j*16 + lrow;
      const int hh = cm >> 6, d = cm & 63;
      #pragma unroll
      for (int i = 0; i < 4; ++i) {
        const int r0 = m0 + wr + i*16 + lquad*4;
        const int bb = r0 >> 9, s = r0 & 511;
        uint2 o;
        o.x = pack2(acc[i][j][0], acc[i][j][1]);
        o.y = pack2(acc[i][j][2], acc[i][j][3]);
        *(uint2*)(vTout + ((size_t)(bb*8 + hh)*64 + d)*512 + s) = o;
      }
    }
    return;
  }

  float* outF = (z == 0) ? outF0 : outF1;
  const bool hasb = ((flags & 1) != 0) && (z == 0);
  const bool dorelu = (flags & 2) != 0;
  #pragma unroll
  for (int j = 0; j < 4; ++j) {
    const int col = n0 + wc + j*16 + lrow;
    const float bv = hasb ? bias[col] : 0.f;
    #pragma unroll
    for (int i = 0; i < 4; ++i) {
      const int r0 = m0 + wr + i*16 + lquad*4;
      #pragma unroll
      for (int v = 0; v < 4; ++v) {
        float val = acc[i][j][v] + bv;
        if (dorelu) val = fmaxf(val, 0.f);
        const size_t off = (size_t)(r0 + v) * N + col;
        if (outB) outB[off] = f2b(val);
        else      outF[off] = val;
      }
    }
  }
}

// ---------------------------------------------------------------------------
// All layers' rel_emb f32 [6][257][64] -> bf16 relB_all [6][272][64]
// ---------------------------------------------------------------------------
__global__ __launch_bounds__(256) void cvt_rel_all(
    const float* __restrict__ rel, u16* __restrict__ relB)
{
  const int i = blockIdx.x*256 + threadIdx.x;
  if (i < 6*257*64) {
    const int l = i / 16448, rem = i % 16448;
    relB[l*17408 + rem] = f2b(rel[i]);
  }
}

// ---------------------------------------------------------------------------
// Barrier-free MFMA flash attention. K and V MFMA B-fragments are loaded
// DIRECTLY from global (K from qkv, V from pre-transposed vT) — the fragment
// layout (n=lane&15, k=quad*8+j) maps to plain 16B per-lane loads. All LDS
// use (Pr table, P C->A round-trip) is wave-private rows; DS pipe is in-order
// per wave => ZERO __syncthreads. XCD swizzle keeps K/V reuse on-die.
// ---------------------------------------------------------------------------
__global__ __launch_bounds__(256) void attn_mfma(
    const u16* __restrict__ qkv, const u16* __restrict__ vT,
    const u16* __restrict__ relB, u16* __restrict__ ctx)
{
  const int id = blockIdx.x;
  const int xcd = id & 7, g = (id >> 3) & 15, qt = id >> 7;
  const int bh = xcd*16 + g;
  const int b = bh >> 3, h = bh & 7;
  const int t = threadIdx.x, w = t >> 6, lane = t & 63;
  const int lr = lane & 15, quad = lane >> 4;

  __shared__ __align__(16) u16 Pr[64*280];  // proj table, wave-private rows
  __shared__ __align__(16) u16 Ps[64*72];   // P tile, wave-private rows

  const size_t token0 = (size_t)b*512 + qt*64;

  // Q A-fragments held in regs: rows w*16+lr, k = quad*8 (+32)
  short8 af0, af1;
  {
    const u16* qp = qkv + (token0 + w*16 + lr)*1536 + h*64 + quad*8;
    af0 = *(const short8*)(qp);
    af1 = *(const short8*)(qp + 32);
  }

  // Pr[q][j] = Q[q] . relB[j]  (each wave: its 16 rows x 272 cols)
  #pragma unroll 4
  for (int nt = 0; nt < 17; ++nt) {
    const u16* rp = relB + (nt*16 + lr)*64 + quad*8;
    short8 rb0 = *(const short8*)(rp);
    short8 rb1 = *(const short8*)(rp + 32);
    floatx4 c = {0.f,0.f,0.f,0.f};
    c = __builtin_amdgcn_mfma_f32_16x16x32_bf16(af0, rb0, c, 0, 0, 0);
    c = __builtin_amdgcn_mfma_f32_16x16x32_bf16(af1, rb1, c, 0, 0, 0);
    #pragma unroll
    for (int r = 0; r < 4; ++r)
      Pr[(w*16 + quad*4 + r)*280 + nt*16 + lr] = f2b(c[r]);
  }

  floatx4 oacc[4];
  floatx4 lacc = {0.f,0.f,0.f,0.f};
  #pragma unroll
  for (int n = 0; n < 4; ++n) { floatx4 zz = {0.f,0.f,0.f,0.f}; oacc[n] = zz; }

  short8 ones;
  #pragma unroll
  for (int i = 0; i < 8; ++i) ones[i] = (short)0x3F80;  // bf16 1.0

  const u16* kbase = qkv + (size_t)b*512*1536 + 512 + h*64;
  const u16* vbase = vT + (size_t)(b*8 + h)*64*512;
  const int qg0 = qt*64 + w*16 + quad*4;

  for (int kt = 0; kt < 8; ++kt) {
    // S = Q . K^T  — K B-frags straight from global (L1/L2-resident)
    floatx4 s4[4];
    #pragma unroll
    for (int nt = 0; nt < 4; ++nt) {
      const u16* kp = kbase + (size_t)(kt*64 + nt*16 + lr)*1536 + quad*8;
      short8 kb0 = *(const short8*)(kp);
      short8 kb1 = *(const short8*)(kp + 32);
      floatx4 c = {0.f,0.f,0.f,0.f};
      c = __builtin_amdgcn_mfma_f32_16x16x32_bf16(af0, kb0, c, 0, 0, 0);
      c = __builtin_amdgcn_mfma_f32_16x16x32_bf16(af1, kb1, c, 0, 0, 0);
      s4[nt] = c;
    }

    // P = exp(S/8 + bias) -> Ps (own rows; in-order DS pipe, no barrier)
    const int kpos = kt*64 + lr;
    #pragma unroll
    for (int r = 0; r < 4; ++r) {
      const int qg = qg0 + r;
      const int prrow = (w*16 + quad*4 + r)*280;
      const int psrow = (w*16 + quad*4 + r)*72;
      #pragma unroll
      for (int nt = 0; nt < 4; ++nt) {
        int dd = (kpos + nt*16) - qg;
        dd = dd < -128 ? -128 : (dd > 128 ? 128 : dd);
        const float sc = fmaf(s4[nt][r], 0.125f, b2f(Pr[prrow + dd + 128]));
        Ps[psrow + nt*16 + lr] = f2b(__expf(sc));
      }
    }

    // O += P . V ; l += P . 1  — V B-frags straight from global vT
    short8 pf0 = *(const short8*)&Ps[(w*16 + lr)*72 + quad*8];
    short8 pf1 = *(const short8*)&Ps[(w*16 + lr)*72 + 32 + quad*8];
    lacc = __builtin_amdgcn_mfma_f32_16x16x32_bf16(pf0, ones, lacc, 0, 0, 0);
    lacc = __builtin_amdgcn_mfma_f32_16x16x32_bf16(pf1, ones, lacc, 0, 0, 0);
    #pragma unroll
    for (int nd = 0; nd < 4; ++nd) {
      const u16* vp = vbase + (size_t)(nd*16 + lr)*512 + kt*64 + quad*8;
      short8 vb0 = *(const short8*)(vp);
      short8 vb1 = *(const short8*)(vp + 32);
      oacc[nd] = __builtin_amdgcn_mfma_f32_16x16x32_bf16(pf0, vb0, oacc[nd], 0, 0, 0);
      oacc[nd] = __builtin_amdgcn_mfma_f32_16x16x32_bf16(pf1, vb1, oacc[nd], 0, 0, 0);
    }
  }

  // epilogue: ctx[token][h*64 + d]; lacc[r] holds row-sum (same in all cols)
  #pragma unroll
  for (int r = 0; r < 4; ++r) {
    const float inv = 1.f / lacc[r];
    u16* cp = ctx + (token0 + w*16 + quad*4 + r)*512 + h*64 + lr;
    #pragma unroll
    for (int nd = 0; nd < 4; ++nd)
      cp[nd*16] = f2b(oacc[nd][r] * inv);
  }
}

// ---------------------------------------------------------------------------
// LayerNorm over D=512: h = LN(res (+ add0) (+ add1)) * g + b -> hf + hb
// ---------------------------------------------------------------------------
__global__ __launch_bounds__(128) void ln_kernel(
    const float* __restrict__ res, const float* __restrict__ add0,
    const float* __restrict__ add1,
    const float* __restrict__ g, const float* __restrict__ be,
    float* __restrict__ hf, u16* __restrict__ hb)
{
  const int row = blockIdx.x, t = threadIdx.x;
  const size_t base = (size_t)row * 512;
  float4 x = *(const float4*)(res + base + t*4);
  if (add0) {
    const float4 a = *(const float4*)(add0 + base + t*4);
    x.x += a.x; x.y += a.y; x.z += a.z; x.w += a.w;
  }
  if (add1) {
    const float4 a = *(const float4*)(add1 + base + t*4);
    x.x += a.x; x.y += a.y; x.z += a.z; x.w += a.w;
  }
  float s = x.x + x.y + x.z + x.w;
  #pragma unroll
  for (int off = 32; off > 0; off >>= 1) s += __shfl_down(s, off);
  __shared__ float red[2];
  const int wv = t >> 6, ln = t & 63;
  if (ln == 0) red[wv] = s;
  __syncthreads();
  const float mean = (red[0] + red[1]) * (1.f/512.f);
  const float dx0 = x.x-mean, dx1 = x.y-mean, dx2 = x.z-mean, dx3 = x.w-mean;
  float vs = dx0*dx0 + dx1*dx1 + dx2*dx2 + dx3*dx3;
  __syncthreads();
  #pragma unroll
  for (int off = 32; off > 0; off >>= 1) vs += __shfl_down(vs, off);
  if (ln == 0) red[wv] = vs;
  __syncthreads();
  const float var = (red[0] + red[1]) * (1.f/512.f);
  const float inv = 1.f / sqrtf(var + 1e-5f);
  const float4 gv = *(const float4*)(g + t*4);
  const float4 bv = *(const float4*)(be + t*4);
  const float y0 = dx0*inv*gv.x + bv.x;
  const float y1 = dx1*inv*gv.y + bv.y;
  const float y2 = dx2*inv*gv.z + bv.z;
  const float y3 = dx3*inv*gv.w + bv.w;
  *(float4*)(hf + base + t*4) = make_float4(y0, y1, y2, y3);
  u32* hp = (u32*)(hb + base + t*4);
  hp[0] = pack2(y0, y1); hp[1] = pack2(y2, y3);
}

// ---------------------------------------------------------------------------
// out[row] = hd1[row][:] . p2_w + p2_b   (256-dot, one wave per row), f32 out
// ---------------------------------------------------------------------------
__global__ __launch_bounds__(256) void head2_kernel(
    const u16* __restrict__ hd1, const float* __restrict__ p2w,
    const float* __restrict__ p2b, float* __restrict__ out)
{
  const int wv = threadIdx.x >> 6, ln = threadIdx.x & 63;
  const int row = blockIdx.x * 4 + wv;
  const u16* hp = hd1 + (size_t)row * 256 + ln*4;
  const u32 h0 = *(const u32*)hp, h1 = *(const u32*)(hp + 2);
  const float4 w = *(const float4*)(p2w + ln*4);
  float acc = lo16(h0)*w.x + hi16(h0)*w.y + lo16(h1)*w.z + hi16(h1)*w.w;
  #pragma unroll
  for (int off = 1; off < 64; off <<= 1) acc += __shfl_xor(acc, off);
  if (ln == 0) out[row] = acc + p2b[0];
}

// ---------------------------------------------------------------------------
extern "C" void kernel_launch(void* const* d_in, const int* in_sizes, int n_in,
                              void* d_out, int out_size, void* d_ws, size_t ws_size,
                              hipStream_t stream) {
  (void)in_sizes; (void)n_in; (void)out_size; (void)ws_size;
  const float* X    = (const float*)d_in[0];
  const float* INW  = (const float*)d_in[1];
  const float* INB  = (const float*)d_in[2];
  const float* WQ   = (const float*)d_in[3];
  const float* WK   = (const float*)d_in[4];
  const float* WV   = (const float*)d_in[5];
  const float* WO   = (const float*)d_in[6];
  const float* BO   = (const float*)d_in[7];
  const float* REL  = (const float*)d_in[8];
  const float* W1   = (const float*)d_in[9];
  const float* B1   = (const float*)d_in[10];
  const float* W2   = (const float*)d_in[11];
  const float* B2   = (const float*)d_in[12];
  const float* LN1G = (const float*)d_in[13];
  const float* LN1B = (const float*)d_in[14];
  const float* LN2G = (const float*)d_in[15];
  const float* LN2B = (const float*)d_in[16];
  const float* ONG  = (const float*)d_in[17];
  const float* ONB  = (const float*)d_in[18];
  const float* P1W  = (const float*)d_in[19];
  const float* P1B  = (const float*)d_in[20];
  const float* P2W  = (const float*)d_in[21];
  const float* P2B  = (const float*)d_in[22];
  float* out = (float*)d_out;

  char* ws = (char*)d_ws;
  u16*   wT    = (u16*)(ws + OFF_WT);
  float* hF    = (float*)(ws + OFF_HF);
  u16*   hB    = (u16*)(ws + OFF_HB);
  u16*   qkv   = (u16*)(ws + OFF_QKV);
  u16*   ctx   = (u16*)(ws + OFF_CTX);
  float* gout0 = (float*)(ws + OFF_GOUT);
  float* gout1 = (float*)(ws + OFF_QKV);   // alias: dead during Wo/FFN2
  u16*   ff    = (u16*)(ws + OFF_FF);
  u16*   hd1   = (u16*)(ws + OFF_HD1);
  u16*   vTb   = (u16*)(ws + OFF_VT);
  u16*   relBa = (u16*)(ws + OFF_RELB);

  transpose_all<<<4640, 256, 0, stream>>>(WQ, WK, WV, WO, W1, W2, P1W, wT);
  cvt_rel_all<<<386, 256, 0, stream>>>(REL, relBa);
  input_proj<<<NTOK, 128, 0, stream>>>(X, INW, INB, hF, hB);

  for (int l = 0; l < NLAYER; ++l) {
    const u16* wTl = wT + (size_t)l * LSTRIDE;
    // QKV fused: [8192,512] @ [512,1536]; Q,K -> qkv bf16, V -> vT transposed
    gemm_bt<<<dim3(768,1), 256, 0, stream>>>(hB, wTl, nullptr, nullptr, nullptr, qkv, vTb,
                                             8192, 1536, 512, 512, 4);
    attn_mfma<<<1024, 256, 0, stream>>>(qkv, vTb, relBa + l*17408, ctx);
    // Wo + bo, split-K=2 -> f32 partials
    gemm_bt<<<dim3(256,2), 256, 0, stream>>>(ctx, wTl + 786432, BO + l*512,
                                             gout0, gout1, nullptr, nullptr,
                                             8192, 512, 512, 256, 1);
    ln_kernel<<<NTOK, 128, 0, stream>>>(hF, gout0, gout1, LN1G + l*512, LN1B + l*512, hF, hB);
    // FFN1: relu(h @ w1 + b1) -> bf16  (overwrites vT scratch - dead)
    gemm_bt<<<dim3(1024,1), 256, 0, stream>>>(hB, wTl + 1048576, B1 + l*2048,
                                              nullptr, nullptr, ff, nullptr,
                                              8192, 2048, 512, 512, 3);
    // FFN2: ff @ w2 + b2, split-K=2 -> f32 partials
    gemm_bt<<<dim3(256,2), 256, 0, stream>>>(ff, wTl + 2097152, B2 + l*512,
                                             gout0, gout1, nullptr, nullptr,
                                             8192, 512, 2048, 1024, 1);
    ln_kernel<<<NTOK, 128, 0, stream>>>(hF, gout0, gout1, LN2G + l*512, LN2B + l*512, hF, hB);
  }
  ln_kernel<<<NTOK, 128, 0, stream>>>(hF, nullptr, nullptr, ONG, ONB, hF, hB);
  // head: relu(h @ p1_w + p1_b) -> bf16 [8192][256]
  gemm_bt<<<dim3(128,1), 256, 0, stream>>>(hB, wT + P1T_OFF, P1B,
                                           nullptr, nullptr, hd1, nullptr,
                                           8192, 256, 512, 512, 3);
  head2_kernel<<<2048, 256, 0, stream>>>(hd1, P2W, P2B, out);
}

// Round 8
// 1271.411 us; speedup vs baseline: 1.1408x; 1.1408x over previous
//
#include <hip/hip_runtime.h>

typedef unsigned short u16;
typedef unsigned int   u32;
typedef short   short8  __attribute__((ext_vector_type(8)));
typedef float   floatx4 __attribute__((ext_vector_type(4)));

#define NTOK 8192
#define SEQ  512
#define NLAYER 6

// ---- workspace layout (bytes) ----
#define OFF_WT   ((size_t)0)          // transposed weights (bf16), 19,005,440 u16
#define OFF_HF   ((size_t)38010880)   // h fp32   [8192][512]
#define OFF_HB   ((size_t)54788096)   // h bf16   [8192][512]
#define OFF_QKV  ((size_t)63176704)   // qkv bf16 [8192][1536] (25.2 MB)
#define OFF_CTX  ((size_t)88342528)   // ctx bf16 [8192][512]
#define OFF_GOUT ((size_t)96731136)   // gout0 fp32 [8192][512]
#define OFF_FF   ((size_t)113508352)  // ff bf16  [8192][2048]  (33.5 MB)
#define OFF_HD1  ((size_t)147062784)  // head1 bf16 [8192][256] (4.2 MB)
// aliases:
//   gout1 (split-K partial, f32 [8192][512]) -> qkv region (dead during Wo/FFN2)
//   vT bf16 [128 bh][64][512] (8.4 MB) -> ff region (dead during attn)
//   relB_all bf16 [6][272][64] (209 KB) -> hd1 region (hd1 written only at end)
#define OFF_VT   OFF_FF
#define OFF_RELB OFF_HD1

#define LSTRIDE 3145728   // wT elems per layer: [QT;KT;VT](1536x512), WoT, w1T(2048x512), w2T(512x2048)
#define P1T_OFF 18874368  // p1T [256][512]

__device__ __forceinline__ float b2f(u16 v) { return __uint_as_float(((u32)v) << 16); }
__device__ __forceinline__ float lo16(u32 v) { return __uint_as_float(v << 16); }
__device__ __forceinline__ float hi16(u32 v) { return __uint_as_float(v & 0xffff0000u); }
__device__ __forceinline__ u16 f2b(float f) {
  u32 x = __float_as_uint(f);
  return (u16)((x + 0x7fffu + ((x >> 16) & 1u)) >> 16);
}
__device__ __forceinline__ u32 pack2(float a, float b) {
  return (u32)f2b(a) | ((u32)f2b(b) << 16);
}

typedef __attribute__((address_space(1))) void* gas_t;
typedef __attribute__((address_space(3))) void* las_t;

// ---------------------------------------------------------------------------
// Transpose all f32 weight matrices into wT (bf16 [N][K] for gemm_bt).
// ---------------------------------------------------------------------------
__global__ __launch_bounds__(256) void transpose_all(
    const float* __restrict__ Wq, const float* __restrict__ Wk,
    const float* __restrict__ Wv, const float* __restrict__ Wo,
    const float* __restrict__ w1, const float* __restrict__ w2,
    const float* __restrict__ p1, u16* __restrict__ wT)
{
  __shared__ u16 tile[64][65];
  const int tb = blockIdx.x;
  const float* src; u16* dst; int R, C, tidx;
  if (tb < 4608) {
    const int l = tb / 768, r = tb % 768;
    const size_t lofs = (size_t)l * LSTRIDE;
    if (r < 256) {
      const int m = r >> 6; tidx = r & 63; R = 512; C = 512;
      const float* bases[4] = {Wq, Wk, Wv, Wo};
      src = bases[m] + (size_t)l * 262144;
      dst = wT + lofs + (size_t)m * 262144;
    } else if (r < 512) {
      tidx = r - 256; R = 512; C = 2048;
      src = w1 + (size_t)l * 1048576; dst = wT + lofs + 1048576;
    } else {
      tidx = r - 512; R = 2048; C = 512;
      src = w2 + (size_t)l * 1048576; dst = wT + lofs + 2097152;
    }
  } else {
    tidx = tb - 4608; R = 512; C = 256;
    src = p1; dst = wT + P1T_OFF;
  }
  const int tcn = C >> 6;
  const int tr = tidx / tcn, tc = tidx % tcn;
  const int th = threadIdx.x;
  {
    const int lr = th >> 2, cg = (th & 3) * 16;
    const float* sp = src + (size_t)(tr*64 + lr) * C + tc*64 + cg;
    float4 f0 = *(const float4*)(sp);
    float4 f1 = *(const float4*)(sp + 4);
    float4 f2 = *(const float4*)(sp + 8);
    float4 f3 = *(const float4*)(sp + 12);
    u16* tp = &tile[lr][cg];
    tp[0]=f2b(f0.x); tp[1]=f2b(f0.y); tp[2]=f2b(f0.z); tp[3]=f2b(f0.w);
    tp[4]=f2b(f1.x); tp[5]=f2b(f1.y); tp[6]=f2b(f1.z); tp[7]=f2b(f1.w);
    tp[8]=f2b(f2.x); tp[9]=f2b(f2.y); tp[10]=f2b(f2.z); tp[11]=f2b(f2.w);
    tp[12]=f2b(f3.x); tp[13]=f2b(f3.y); tp[14]=f2b(f3.z); tp[15]=f2b(f3.w);
  }
  __syncthreads();
  {
    const int oc = th >> 2, rg = (th & 3) * 16;
    u32 wds[8];
    #pragma unroll
    for (int i = 0; i < 8; ++i)
      wds[i] = (u32)tile[rg + 2*i][oc] | ((u32)tile[rg + 2*i + 1][oc] << 16);
    u16* dp = dst + (size_t)(tc*64 + oc) * R + tr*64 + rg;
    uint4 o0; o0.x=wds[0]; o0.y=wds[1]; o0.z=wds[2]; o0.w=wds[3];
    uint4 o1; o1.x=wds[4]; o1.y=wds[5]; o1.z=wds[6]; o1.w=wds[7];
    *(uint4*)dp = o0;
    *(uint4*)(dp + 8) = o1;
  }
}

// ---------------------------------------------------------------------------
// h = x @ in_w + in_b + sinusoidal_pe   (K=50, exact f32)
// ---------------------------------------------------------------------------
__global__ __launch_bounds__(128) void input_proj(
    const float* __restrict__ x, const float* __restrict__ w, const float* __restrict__ ib,
    float* __restrict__ hf, u16* __restrict__ hb)
{
  const int row = blockIdx.x, t = threadIdx.x;
  const int s = row & (SEQ - 1);
  __shared__ float xs[50];
  if (t < 50) xs[t] = x[row*50 + t];
  __syncthreads();
  #pragma unroll
  for (int rep = 0; rep < 4; ++rep) {
    const int d = rep*128 + t;
    float acc = ib[d];
    #pragma unroll
    for (int i = 0; i < 50; ++i) acc += xs[i] * w[i*512 + d];
    const int ii = d >> 1;
    const float dv = __expf((float)(2*ii) * -0.017988946f); // -ln(10000)/512
    const float ang = (float)s * dv;
    const float pe = (d & 1) ? cosf(ang) : sinf(ang);
    const float v = acc + pe;
    hf[(size_t)row*512 + d] = v;
    hb[(size_t)row*512 + d] = f2b(v);
  }
}

// ---------------------------------------------------------------------------
// C[M][N] = A[M][K] @ Bt[N][K]^T over k in [z*kLen, (z+1)*kLen)
// BK=64: two m97-style 128x32 images per matrix, one barrier pair per 64 k.
// z = blockIdx.y. z==0 gets +bias; relu per flags bit1.
// flags bit2: blocks with n0>=1024 write V directly in vT-transposed layout.
// ---------------------------------------------------------------------------
__global__ __launch_bounds__(256) void gemm_bt(
    const u16* __restrict__ A, const u16* __restrict__ Bt,
    const float* __restrict__ bias,
    float* __restrict__ outF0, float* __restrict__ outF1, u16* __restrict__ outB,
    u16* __restrict__ vTout,
    const int M, const int N, const int K, const int kLen, const int flags)
{
  __shared__ __align__(16) u16 As[2*128*32];
  __shared__ __align__(16) u16 Bs[2*128*32];
  const int nb = N >> 7;
  const int bm = blockIdx.x / nb, bn = blockIdx.x % nb;
  const int z = blockIdx.y;
  const int kOff = z * kLen;
  const int m0 = bm << 7, n0 = bn << 7;
  const int tid = threadIdx.x;
  const int wave = tid >> 6, lane = tid & 63;
  const int wr = (wave >> 1) << 6, wc = (wave & 1) << 6;
  const int lrow = lane & 15, lquad = lane >> 4;

  floatx4 acc[4][4];
  #pragma unroll
  for (int i = 0; i < 4; ++i)
    #pragma unroll
    for (int j = 0; j < 4; ++j) { floatx4 zz = {0.f,0.f,0.f,0.f}; acc[i][j] = zz; }

  const u16* a0p = A  + (size_t)m0 * K + kOff;
  const u16* b0p = Bt + (size_t)n0 * K + kOff;
  const int c0 = tid, c1 = 256 + tid;
  const int ar0 = c0 >> 2, as0 = (c0 & 3) * 8;
  const int ar1 = c1 >> 2, as1 = (c1 & 3) * 8;

  for (int k0 = 0; k0 < kLen; k0 += 64) {
    #pragma unroll
    for (int hh = 0; hh < 2; ++hh) {
      const int kk = k0 + hh*32;
      __builtin_amdgcn_global_load_lds((gas_t)(a0p + (size_t)ar0*K + kk + as0), (las_t)(&As[hh*4096 + c0*8]), 16, 0, 0);
      __builtin_amdgcn_global_load_lds((gas_t)(a0p + (size_t)ar1*K + kk + as1), (las_t)(&As[hh*4096 + c1*8]), 16, 0, 0);
      __builtin_amdgcn_global_load_lds((gas_t)(b0p + (size_t)ar0*K + kk + as0), (las_t)(&Bs[hh*4096 + c0*8]), 16, 0, 0);
      __builtin_amdgcn_global_load_lds((gas_t)(b0p + (size_t)ar1*K + kk + as1), (las_t)(&Bs[hh*4096 + c1*8]), 16, 0, 0);
    }
    __syncthreads();
    #pragma unroll
    for (int hh = 0; hh < 2; ++hh) {
      short8 af[4], bf[4];
      #pragma unroll
      for (int i = 0; i < 4; ++i) af[i] = *(const short8*)&As[hh*4096 + (wr + i*16 + lrow)*32 + lquad*8];
      #pragma unroll
      for (int j = 0; j < 4; ++j) bf[j] = *(const short8*)&Bs[hh*4096 + (wc + j*16 + lrow)*32 + lquad*8];
      #pragma unroll
      for (int i = 0; i < 4; ++i)
        #pragma unroll
        for (int j = 0; j < 4; ++j)
          acc[i][j] = __builtin_amdgcn_mfma_f32_16x16x32_bf16(af[i], bf[j], acc[i][j], 0, 0, 0);
    }
    __syncthreads();
  }

  if ((flags & 4) && n0 >= 1024) {
    // V block of QKV: write directly into vT[(b*8+h)*64+d][s] (bf16)
    #pragma unroll
    for (int j = 0; j < 4; ++j) {
      const int cm = (n0 - 1024) + wc + j*16 + lrow;
      const int hh = cm >> 6, d = cm & 63;
      #pragma unroll
      for (int i = 0; i < 4; ++i) {
        const int r0 = m0 + wr + i*16 + lquad*4;
        const int bb = r0 >> 9, s = r0 & 511;
        uint2 o;
        o.x = pack2(acc[i][j][0], acc[i][j][1]);
        o.y = pack2(acc[i][j][2], acc[i][j][3]);
        *(uint2*)(vTout + ((size_t)(bb*8 + hh)*64 + d)*512 + s) = o;
      }
    }
    return;
  }

  float* outF = (z == 0) ? outF0 : outF1;
  const bool hasb = ((flags & 1) != 0) && (z == 0);
  const bool dorelu = (flags & 2) != 0;
  #pragma unroll
  for (int j = 0; j < 4; ++j) {
    const int col = n0 + wc + j*16 + lrow;
    const float bv = hasb ? bias[col] : 0.f;
    #pragma unroll
    for (int i = 0; i < 4; ++i) {
      const int r0 = m0 + wr + i*16 + lquad*4;
      #pragma unroll
      for (int v = 0; v < 4; ++v) {
        float val = acc[i][j][v] + bv;
        if (dorelu) val = fmaxf(val, 0.f);
        const size_t off = (size_t)(r0 + v) * N + col;
        if (outB) outB[off] = f2b(val);
        else      outF[off] = val;
      }
    }
  }
}

// ---------------------------------------------------------------------------
// All layers' rel_emb f32 [6][257][64] -> bf16 relB_all [6][272][64]
// ---------------------------------------------------------------------------
__global__ __launch_bounds__(256) void cvt_rel_all(
    const float* __restrict__ rel, u16* __restrict__ relB)
{
  const int i = blockIdx.x*256 + threadIdx.x;
  if (i < 6*257*64) {
    const int l = i / 16448, rem = i % 16448;
    relB[l*17408 + rem] = f2b(rel[i]);
  }
}

// ---------------------------------------------------------------------------
// MFMA flash attention (R6 LDS-staged structure + register prefetch of the
// next K/V tile so global latency hides behind S/softmax/PV compute).
// Max-free softmax (scores provably small), l via ones-MFMA.
// XCD swizzle: all 8 qt-blocks of one (b,h) share id%8 -> same XCD L2.
// LDS 54272 B -> 3 blocks/CU.
// ---------------------------------------------------------------------------
__global__ __launch_bounds__(256) void attn_mfma(
    const u16* __restrict__ qkv, const u16* __restrict__ vT,
    const u16* __restrict__ relB, u16* __restrict__ ctx)
{
  const int id = blockIdx.x;
  const int xcd = id & 7, g = (id >> 3) & 15, qt = id >> 7;
  const int bh = xcd*16 + g;
  const int b = bh >> 3, h = bh & 7;
  const int t = threadIdx.x, w = t >> 6, lane = t & 63;
  const int lr = lane & 15, quad = lane >> 4;

  __shared__ __align__(16) u16 Ks[64*72];   // K tile, then aliased as P tile
  __shared__ __align__(16) u16 Vs[64*72];
  __shared__ __align__(16) u16 Pr[64*280];  // proj table, wave-private rows

  const size_t token0 = (size_t)b*512 + qt*64;

  // Q A-fragments held in regs: rows w*16+lr, k = quad*8 (+32)
  short8 af0, af1;
  {
    const u16* qp = qkv + (token0 + w*16 + lr)*1536 + h*64 + quad*8;
    af0 = *(const short8*)(qp);
    af1 = *(const short8*)(qp + 32);
  }

  // Pr[q][j] = Q[q] . relB[j]  (each wave: its 16 rows x 272 cols)
  #pragma unroll 4
  for (int nt = 0; nt < 17; ++nt) {
    const u16* rp = relB + (nt*16 + lr)*64 + quad*8;
    short8 rb0 = *(const short8*)(rp);
    short8 rb1 = *(const short8*)(rp + 32);
    floatx4 c = {0.f,0.f,0.f,0.f};
    c = __builtin_amdgcn_mfma_f32_16x16x32_bf16(af0, rb0, c, 0, 0, 0);
    c = __builtin_amdgcn_mfma_f32_16x16x32_bf16(af1, rb1, c, 0, 0, 0);
    #pragma unroll
    for (int r = 0; r < 4; ++r)
      Pr[(w*16 + quad*4 + r)*280 + nt*16 + lr] = f2b(c[r]);
  }

  floatx4 oacc[4];
  floatx4 lacc = {0.f,0.f,0.f,0.f};
  #pragma unroll
  for (int n = 0; n < 4; ++n) { floatx4 zz = {0.f,0.f,0.f,0.f}; oacc[n] = zz; }

  short8 ones;
  #pragma unroll
  for (int i = 0; i < 8; ++i) ones[i] = (short)0x3F80;  // bf16 1.0

  const int srow = t >> 2, scol = (t & 3) * 16;
  const u16* kbase = qkv + (size_t)b*512*1536 + 512 + h*64;
  const u16* vbase = vT + (size_t)(b*8 + h)*64*512;
  const int qg0 = qt*64 + w*16 + quad*4;

  // prefetch kt=0 tile into regs
  uint4 kr0, kr1, vr0, vr1;
  {
    const u16* kp = kbase + (size_t)(srow)*1536 + scol;
    kr0 = *(const uint4*)kp; kr1 = *(const uint4*)(kp + 8);
    const u16* vp = vbase + (size_t)srow*512 + scol;
    vr0 = *(const uint4*)vp; vr1 = *(const uint4*)(vp + 8);
  }

  for (int kt = 0; kt < 8; ++kt) {
    __syncthreads();  // prev iter's P/V reads done before overwrite
    // stage prefetched K/V tile into padded LDS
    *(uint4*)&Ks[srow*72 + scol]     = kr0;
    *(uint4*)&Ks[srow*72 + scol + 8] = kr1;
    *(uint4*)&Vs[srow*72 + scol]     = vr0;
    *(uint4*)&Vs[srow*72 + scol + 8] = vr1;
    // issue next tile's global loads now; they complete during compute below
    if (kt < 7) {
      const u16* kp = kbase + (size_t)((kt+1)*64 + srow)*1536 + scol;
      kr0 = *(const uint4*)kp; kr1 = *(const uint4*)(kp + 8);
      const u16* vp = vbase + (size_t)srow*512 + (kt+1)*64 + scol;
      vr0 = *(const uint4*)vp; vr1 = *(const uint4*)(vp + 8);
    }
    __syncthreads();

    // S = Q . K^T  (wave's 16 q rows x 64 k cols)
    floatx4 s4[4];
    #pragma unroll
    for (int nt = 0; nt < 4; ++nt) {
      short8 kb0 = *(const short8*)&Ks[(nt*16 + lr)*72 + quad*8];
      short8 kb1 = *(const short8*)&Ks[(nt*16 + lr)*72 + 32 + quad*8];
      floatx4 c = {0.f,0.f,0.f,0.f};
      c = __builtin_amdgcn_mfma_f32_16x16x32_bf16(af0, kb0, c, 0, 0, 0);
      c = __builtin_amdgcn_mfma_f32_16x16x32_bf16(af1, kb1, c, 0, 0, 0);
      s4[nt] = c;
    }
    __syncthreads();  // all waves done reading Ks before P overwrites it

    // P = exp(S/8 + bias); write into Ks region (own rows only)
    const int kpos = kt*64 + lr;
    #pragma unroll
    for (int r = 0; r < 4; ++r) {
      const int qg = qg0 + r;
      const int prrow = (w*16 + quad*4 + r)*280;
      const int psrow = (w*16 + quad*4 + r)*72;
      #pragma unroll
      for (int nt = 0; nt < 4; ++nt) {
        int dd = (kpos + nt*16) - qg;
        dd = dd < -128 ? -128 : (dd > 128 ? 128 : dd);
        const float sc = fmaf(s4[nt][r], 0.125f, b2f(Pr[prrow + dd + 128]));
        Ks[psrow + nt*16 + lr] = f2b(__expf(sc));
      }
    }

    // O += P . V ; l += P . 1  (A-frag rows are wave-private: no barrier)
    short8 pf0 = *(const short8*)&Ks[(w*16 + lr)*72 + quad*8];
    short8 pf1 = *(const short8*)&Ks[(w*16 + lr)*72 + 32 + quad*8];
    lacc = __builtin_amdgcn_mfma_f32_16x16x32_bf16(pf0, ones, lacc, 0, 0, 0);
    lacc = __builtin_amdgcn_mfma_f32_16x16x32_bf16(pf1, ones, lacc, 0, 0, 0);
    #pragma unroll
    for (int nd = 0; nd < 4; ++nd) {
      short8 vb0 = *(const short8*)&Vs[(nd*16 + lr)*72 + quad*8];
      short8 vb1 = *(const short8*)&Vs[(nd*16 + lr)*72 + 32 + quad*8];
      oacc[nd] = __builtin_amdgcn_mfma_f32_16x16x32_bf16(pf0, vb0, oacc[nd], 0, 0, 0);
      oacc[nd] = __builtin_amdgcn_mfma_f32_16x16x32_bf16(pf1, vb1, oacc[nd], 0, 0, 0);
    }
  }

  // epilogue: ctx[token][h*64 + d]; lacc[r] holds row-sum (same in all cols)
  #pragma unroll
  for (int r = 0; r < 4; ++r) {
    const float inv = 1.f / lacc[r];
    u16* cp = ctx + (token0 + w*16 + quad*4 + r)*512 + h*64 + lr;
    #pragma unroll
    for (int nd = 0; nd < 4; ++nd)
      cp[nd*16] = f2b(oacc[nd][r] * inv);
  }
}

// ---------------------------------------------------------------------------
// LayerNorm over D=512: h = LN(res (+ add0) (+ add1)) * g + b -> hf + hb
// ---------------------------------------------------------------------------
__global__ __launch_bounds__(128) void ln_kernel(
    const float* __restrict__ res, const float* __restrict__ add0,
    const float* __restrict__ add1,
    const float* __restrict__ g, const float* __restrict__ be,
    float* __restrict__ hf, u16* __restrict__ hb)
{
  const int row = blockIdx.x, t = threadIdx.x;
  const size_t base = (size_t)row * 512;
  float4 x = *(const float4*)(res + base + t*4);
  if (add0) {
    const float4 a = *(const float4*)(add0 + base + t*4);
    x.x += a.x; x.y += a.y; x.z += a.z; x.w += a.w;
  }
  if (add1) {
    const float4 a = *(const float4*)(add1 + base + t*4);
    x.x += a.x; x.y += a.y; x.z += a.z; x.w += a.w;
  }
  float s = x.x + x.y + x.z + x.w;
  #pragma unroll
  for (int off = 32; off > 0; off >>= 1) s += __shfl_down(s, off);
  __shared__ float red[2];
  const int wv = t >> 6, ln = t & 63;
  if (ln == 0) red[wv] = s;
  __syncthreads();
  const float mean = (red[0] + red[1]) * (1.f/512.f);
  const float dx0 = x.x-mean, dx1 = x.y-mean, dx2 = x.z-mean, dx3 = x.w-mean;
  float vs = dx0*dx0 + dx1*dx1 + dx2*dx2 + dx3*dx3;
  __syncthreads();
  #pragma unroll
  for (int off = 32; off > 0; off >>= 1) vs += __shfl_down(vs, off);
  if (ln == 0) red[wv] = vs;
  __syncthreads();
  const float var = (red[0] + red[1]) * (1.f/512.f);
  const float inv = 1.f / sqrtf(var + 1e-5f);
  const float4 gv = *(const float4*)(g + t*4);
  const float4 bv = *(const float4*)(be + t*4);
  const float y0 = dx0*inv*gv.x + bv.x;
  const float y1 = dx1*inv*gv.y + bv.y;
  const float y2 = dx2*inv*gv.z + bv.z;
  const float y3 = dx3*inv*gv.w + bv.w;
  *(float4*)(hf + base + t*4) = make_float4(y0, y1, y2, y3);
  u32* hp = (u32*)(hb + base + t*4);
  hp[0] = pack2(y0, y1); hp[1] = pack2(y2, y3);
}

// ---------------------------------------------------------------------------
// out[row] = hd1[row][:] . p2_w + p2_b   (256-dot, one wave per row), f32 out
// ---------------------------------------------------------------------------
__global__ __launch_bounds__(256) void head2_kernel(
    const u16* __restrict__ hd1, const float* __restrict__ p2w,
    const float* __restrict__ p2b, float* __restrict__ out)
{
  const int wv = threadIdx.x >> 6, ln = threadIdx.x & 63;
  const int row = blockIdx.x * 4 + wv;
  const u16* hp = hd1 + (size_t)row * 256 + ln*4;
  const u32 h0 = *(const u32*)hp, h1 = *(const u32*)(hp + 2);
  const float4 w = *(const float4*)(p2w + ln*4);
  float acc = lo16(h0)*w.x + hi16(h0)*w.y + lo16(h1)*w.z + hi16(h1)*w.w;
  #pragma unroll
  for (int off = 1; off < 64; off <<= 1) acc += __shfl_xor(acc, off);
  if (ln == 0) out[row] = acc + p2b[0];
}

// ---------------------------------------------------------------------------
extern "C" void kernel_launch(void* const* d_in, const int* in_sizes, int n_in,
                              void* d_out, int out_size, void* d_ws, size_t ws_size,
                              hipStream_t stream) {
  (void)in_sizes; (void)n_in; (void)out_size; (void)ws_size;
  const float* X    = (const float*)d_in[0];
  const float* INW  = (const float*)d_in[1];
  const float* INB  = (const float*)d_in[2];
  const float* WQ   = (const float*)d_in[3];
  const float* WK   = (const float*)d_in[4];
  const float* WV   = (const float*)d_in[5];
  const float* WO   = (const float*)d_in[6];
  const float* BO   = (const float*)d_in[7];
  const float* REL  = (const float*)d_in[8];
  const float* W1   = (const float*)d_in[9];
  const float* B1   = (const float*)d_in[10];
  const float* W2   = (const float*)d_in[11];
  const float* B2   = (const float*)d_in[12];
  const float* LN1G = (const float*)d_in[13];
  const float* LN1B = (const float*)d_in[14];
  const float* LN2G = (const float*)d_in[15];
  const float* LN2B = (const float*)d_in[16];
  const float* ONG  = (const float*)d_in[17];
  const float* ONB  = (const float*)d_in[18];
  const float* P1W  = (const float*)d_in[19];
  const float* P1B  = (const float*)d_in[20];
  const float* P2W  = (const float*)d_in[21];
  const float* P2B  = (const float*)d_in[22];
  float* out = (float*)d_out;

  char* ws = (char*)d_ws;
  u16*   wT    = (u16*)(ws + OFF_WT);
  float* hF    = (float*)(ws + OFF_HF);
  u16*   hB    = (u16*)(ws + OFF_HB);
  u16*   qkv   = (u16*)(ws + OFF_QKV);
  u16*   ctx   = (u16*)(ws + OFF_CTX);
  float* gout0 = (float*)(ws + OFF_GOUT);
  float* gout1 = (float*)(ws + OFF_QKV);   // alias: dead during Wo/FFN2
  u16*   ff    = (u16*)(ws + OFF_FF);
  u16*   hd1   = (u16*)(ws + OFF_HD1);
  u16*   vTb   = (u16*)(ws + OFF_VT);
  u16*   relBa = (u16*)(ws + OFF_RELB);

  transpose_all<<<4640, 256, 0, stream>>>(WQ, WK, WV, WO, W1, W2, P1W, wT);
  cvt_rel_all<<<386, 256, 0, stream>>>(REL, relBa);
  input_proj<<<NTOK, 128, 0, stream>>>(X, INW, INB, hF, hB);

  for (int l = 0; l < NLAYER; ++l) {
    const u16* wTl = wT + (size_t)l * LSTRIDE;
    // QKV fused: [8192,512] @ [512,1536]; Q,K -> qkv bf16, V -> vT transposed
    gemm_bt<<<dim3(768,1), 256, 0, stream>>>(hB, wTl, nullptr, nullptr, nullptr, qkv, vTb,
                                             8192, 1536, 512, 512, 4);
    attn_mfma<<<1024, 256, 0, stream>>>(qkv, vTb, relBa + l*17408, ctx);
    // Wo + bo, split-K=2 -> f32 partials
    gemm_bt<<<dim3(256,2), 256, 0, stream>>>(ctx, wTl + 786432, BO + l*512,
                                             gout0, gout1, nullptr, nullptr,
                                             8192, 512, 512, 256, 1);
    ln_kernel<<<NTOK, 128, 0, stream>>>(hF, gout0, gout1, LN1G + l*512, LN1B + l*512, hF, hB);
    // FFN1: relu(h @ w1 + b1) -> bf16  (overwrites vT scratch - dead)
    gemm_bt<<<dim3(1024,1), 256, 0, stream>>>(hB, wTl + 1048576, B1 + l*2048,
                                              nullptr, nullptr, ff, nullptr,
                                              8192, 2048, 512, 512, 3);
    // FFN2: ff @ w2 + b2, split-K=2 -> f32 partials
    gemm_bt<<<dim3(256,2), 256, 0, stream>>>(ff, wTl + 2097152, B2 + l*512,
                                             gout0, gout1, nullptr, nullptr,
                                             8192, 512, 2048, 1024, 1);
    ln_kernel<<<NTOK, 128, 0, stream>>>(hF, gout0, gout1, LN2G + l*512, LN2B + l*512, hF, hB);
  }
  ln_kernel<<<NTOK, 128, 0, stream>>>(hF, nullptr, nullptr, ONG, ONB, hF, hB);
  // head: relu(h @ p1_w + p1_b) -> bf16 [8192][256]
  gemm_bt<<<dim3(128,1), 256, 0, stream>>>(hB, wT + P1T_OFF, P1B,
                                           nullptr, nullptr, hd1, nullptr,
                                           8192, 256, 512, 512, 3);
  head2_kernel<<<2048, 256, 0, stream>>>(hd1, P2W, P2B, out);
}

// Round 9
// 1218.889 us; speedup vs baseline: 1.1900x; 1.0431x over previous
//
#include <hip/hip_runtime.h>

typedef unsigned short u16;
typedef unsigned int   u32;
typedef short   short8  __attribute__((ext_vector_type(8)));
typedef float   floatx4 __attribute__((ext_vector_type(4)));

#define NTOK 8192
#define SEQ  512
#define NLAYER 6

// ---- workspace layout (bytes) ----
#define OFF_WT   ((size_t)0)          // transposed weights (bf16), 19,005,440 u16
#define OFF_HB   ((size_t)38010880)   // h bf16   [8192][512] (residual stream)
#define OFF_QKV  ((size_t)46399488)   // qkv bf16 [8192][1536] (25.2 MB)
#define OFF_CTX  ((size_t)71565312)   // ctx bf16 [8192][512]
#define OFF_GOUT ((size_t)79953920)   // gout0 fp32 [8192][512]
#define OFF_FF   ((size_t)96731136)   // ff bf16  [8192][2048]  (33.5 MB)
#define OFF_HD1  ((size_t)130285568)  // head1 bf16 [8192][256] (4.2 MB)
// aliases:
//   gout1 (split-K partial, f32 [8192][512]) -> qkv region (dead during Wo/FFN2)
//   vT bf16 [128 bh][64][512] (8.4 MB) -> ff region (dead during attn)
//   relB_all bf16 [6][272][64] (209 KB) -> hd1 region (hd1 written only at end)
#define OFF_VT   OFF_FF
#define OFF_RELB OFF_HD1

#define LSTRIDE 3145728   // wT elems per layer: [QT;KT;VT](1536x512), WoT, w1T(2048x512), w2T(512x2048)
#define P1T_OFF 18874368  // p1T [256][512]

__device__ __forceinline__ float b2f(u16 v) { return __uint_as_float(((u32)v) << 16); }
__device__ __forceinline__ float lo16(u32 v) { return __uint_as_float(v << 16); }
__device__ __forceinline__ float hi16(u32 v) { return __uint_as_float(v & 0xffff0000u); }
__device__ __forceinline__ u16 f2b(float f) {
  u32 x = __float_as_uint(f);
  return (u16)((x + 0x7fffu + ((x >> 16) & 1u)) >> 16);
}
__device__ __forceinline__ u32 pack2(float a, float b) {
  return (u32)f2b(a) | ((u32)f2b(b) << 16);
}

typedef __attribute__((address_space(1))) void* gas_t;
typedef __attribute__((address_space(3))) void* las_t;

// ---------------------------------------------------------------------------
// Transpose all f32 weight matrices into wT (bf16 [N][K] for gemm_bt).
// ---------------------------------------------------------------------------
__global__ __launch_bounds__(256) void transpose_all(
    const float* __restrict__ Wq, const float* __restrict__ Wk,
    const float* __restrict__ Wv, const float* __restrict__ Wo,
    const float* __restrict__ w1, const float* __restrict__ w2,
    const float* __restrict__ p1, u16* __restrict__ wT)
{
  __shared__ u16 tile[64][65];
  const int tb = blockIdx.x;
  const float* src; u16* dst; int R, C, tidx;
  if (tb < 4608) {
    const int l = tb / 768, r = tb % 768;
    const size_t lofs = (size_t)l * LSTRIDE;
    if (r < 256) {
      const int m = r >> 6; tidx = r & 63; R = 512; C = 512;
      const float* bases[4] = {Wq, Wk, Wv, Wo};
      src = bases[m] + (size_t)l * 262144;
      dst = wT + lofs + (size_t)m * 262144;
    } else if (r < 512) {
      tidx = r - 256; R = 512; C = 2048;
      src = w1 + (size_t)l * 1048576; dst = wT + lofs + 1048576;
    } else {
      tidx = r - 512; R = 2048; C = 512;
      src = w2 + (size_t)l * 1048576; dst = wT + lofs + 2097152;
    }
  } else {
    tidx = tb - 4608; R = 512; C = 256;
    src = p1; dst = wT + P1T_OFF;
  }
  const int tcn = C >> 6;
  const int tr = tidx / tcn, tc = tidx % tcn;
  const int th = threadIdx.x;
  {
    const int lr = th >> 2, cg = (th & 3) * 16;
    const float* sp = src + (size_t)(tr*64 + lr) * C + tc*64 + cg;
    float4 f0 = *(const float4*)(sp);
    float4 f1 = *(const float4*)(sp + 4);
    float4 f2 = *(const float4*)(sp + 8);
    float4 f3 = *(const float4*)(sp + 12);
    u16* tp = &tile[lr][cg];
    tp[0]=f2b(f0.x); tp[1]=f2b(f0.y); tp[2]=f2b(f0.z); tp[3]=f2b(f0.w);
    tp[4]=f2b(f1.x); tp[5]=f2b(f1.y); tp[6]=f2b(f1.z); tp[7]=f2b(f1.w);
    tp[8]=f2b(f2.x); tp[9]=f2b(f2.y); tp[10]=f2b(f2.z); tp[11]=f2b(f2.w);
    tp[12]=f2b(f3.x); tp[13]=f2b(f3.y); tp[14]=f2b(f3.z); tp[15]=f2b(f3.w);
  }
  __syncthreads();
  {
    const int oc = th >> 2, rg = (th & 3) * 16;
    u32 wds[8];
    #pragma unroll
    for (int i = 0; i < 8; ++i)
      wds[i] = (u32)tile[rg + 2*i][oc] | ((u32)tile[rg + 2*i + 1][oc] << 16);
    u16* dp = dst + (size_t)(tc*64 + oc) * R + tr*64 + rg;
    uint4 o0; o0.x=wds[0]; o0.y=wds[1]; o0.z=wds[2]; o0.w=wds[3];
    uint4 o1; o1.x=wds[4]; o1.y=wds[5]; o1.z=wds[6]; o1.w=wds[7];
    *(uint4*)dp = o0;
    *(uint4*)(dp + 8) = o1;
  }
}

// ---------------------------------------------------------------------------
// h = x @ in_w + in_b + sinusoidal_pe   (K=50, exact f32) -> bf16
// ---------------------------------------------------------------------------
__global__ __launch_bounds__(128) void input_proj(
    const float* __restrict__ x, const float* __restrict__ w, const float* __restrict__ ib,
    u16* __restrict__ hb)
{
  const int row = blockIdx.x, t = threadIdx.x;
  const int s = row & (SEQ - 1);
  __shared__ float xs[50];
  if (t < 50) xs[t] = x[row*50 + t];
  __syncthreads();
  #pragma unroll
  for (int rep = 0; rep < 4; ++rep) {
    const int d = rep*128 + t;
    float acc = ib[d];
    #pragma unroll
    for (int i = 0; i < 50; ++i) acc += xs[i] * w[i*512 + d];
    const int ii = d >> 1;
    const float dv = __expf((float)(2*ii) * -0.017988946f); // -ln(10000)/512
    const float ang = (float)s * dv;
    const float pe = (d & 1) ? cosf(ang) : sinf(ang);
    hb[(size_t)row*512 + d] = f2b(acc + pe);
  }
}

// ---------------------------------------------------------------------------
// C[M][N] = A[M][K] @ Bt[N][K]^T over k in [z*kLen, (z+1)*kLen)
// BK=64. XCD swizzle: bm = bmHigh*8 + (id&7) so all n-tiles of one m-row
// share id%8 (same XCD) -> A-tile fetched once per XCD, not ~8x chip-wide.
// z = blockIdx.y. z==0 gets +bias; relu per flags bit1.
// flags bit2: blocks with n0>=1024 write V directly in vT-transposed layout.
// ---------------------------------------------------------------------------
__global__ __launch_bounds__(256) void gemm_bt(
    const u16* __restrict__ A, const u16* __restrict__ Bt,
    const float* __restrict__ bias,
    float* __restrict__ outF0, float* __restrict__ outF1, u16* __restrict__ outB,
    u16* __restrict__ vTout,
    const int M, const int N, const int K, const int kLen, const int flags)
{
  __shared__ __align__(16) u16 As[2*128*32];
  __shared__ __align__(16) u16 Bs[2*128*32];
  const int nb = N >> 7;
  // mb = M/128 = 64 always; bm-based XCD swizzle (mb/8 = 8)
  const int id = blockIdx.x;
  const int xcd = id & 7, rest = id >> 3;
  const int bm = (rest & 7) * 8 + xcd;
  const int bn = rest >> 3;
  const int z = blockIdx.y;
  const int kOff = z * kLen;
  const int m0 = bm << 7, n0 = bn << 7;
  const int tid = threadIdx.x;
  const int wave = tid >> 6, lane = tid & 63;
  const int wr = (wave >> 1) << 6, wc = (wave & 1) << 6;
  const int lrow = lane & 15, lquad = lane >> 4;
  (void)nb;

  floatx4 acc[4][4];
  #pragma unroll
  for (int i = 0; i < 4; ++i)
    #pragma unroll
    for (int j = 0; j < 4; ++j) { floatx4 zz = {0.f,0.f,0.f,0.f}; acc[i][j] = zz; }

  const u16* a0p = A  + (size_t)m0 * K + kOff;
  const u16* b0p = Bt + (size_t)n0 * K + kOff;
  const int c0 = tid, c1 = 256 + tid;
  const int ar0 = c0 >> 2, as0 = (c0 & 3) * 8;
  const int ar1 = c1 >> 2, as1 = (c1 & 3) * 8;

  for (int k0 = 0; k0 < kLen; k0 += 64) {
    #pragma unroll
    for (int hh = 0; hh < 2; ++hh) {
      const int kk = k0 + hh*32;
      __builtin_amdgcn_global_load_lds((gas_t)(a0p + (size_t)ar0*K + kk + as0), (las_t)(&As[hh*4096 + c0*8]), 16, 0, 0);
      __builtin_amdgcn_global_load_lds((gas_t)(a0p + (size_t)ar1*K + kk + as1), (las_t)(&As[hh*4096 + c1*8]), 16, 0, 0);
      __builtin_amdgcn_global_load_lds((gas_t)(b0p + (size_t)ar0*K + kk + as0), (las_t)(&Bs[hh*4096 + c0*8]), 16, 0, 0);
      __builtin_amdgcn_global_load_lds((gas_t)(b0p + (size_t)ar1*K + kk + as1), (las_t)(&Bs[hh*4096 + c1*8]), 16, 0, 0);
    }
    __syncthreads();
    #pragma unroll
    for (int hh = 0; hh < 2; ++hh) {
      short8 af[4], bf[4];
      #pragma unroll
      for (int i = 0; i < 4; ++i) af[i] = *(const short8*)&As[hh*4096 + (wr + i*16 + lrow)*32 + lquad*8];
      #pragma unroll
      for (int j = 0; j < 4; ++j) bf[j] = *(const short8*)&Bs[hh*4096 + (wc + j*16 + lrow)*32 + lquad*8];
      #pragma unroll
      for (int i = 0; i < 4; ++i)
        #pragma unroll
        for (int j = 0; j < 4; ++j)
          acc[i][j] = __builtin_amdgcn_mfma_f32_16x16x32_bf16(af[i], bf[j], acc[i][j], 0, 0, 0);
    }
    __syncthreads();
  }

  if ((flags & 4) && n0 >= 1024) {
    // V block of QKV: write directly into vT[(b*8+h)*64+d][s] (bf16)
    #pragma unroll
    for (int j = 0; j < 4; ++j) {
      const int cm = (n0 - 1024) + wc + j*16 + lrow;
      const int hh = cm >> 6, d = cm & 63;
      #pragma unroll
      for (int i = 0; i < 4; ++i) {
        const int r0 = m0 + wr + i*16 + lquad*4;
        const int bb = r0 >> 9, s = r0 & 511;
        uint2 o;
        o.x = pack2(acc[i][j][0], acc[i][j][1]);
        o.y = pack2(acc[i][j][2], acc[i][j][3]);
        *(uint2*)(vTout + ((size_t)(bb*8 + hh)*64 + d)*512 + s) = o;
      }
    }
    return;
  }

  float* outF = (z == 0) ? outF0 : outF1;
  const bool hasb = ((flags & 1) != 0) && (z == 0);
  const bool dorelu = (flags & 2) != 0;
  #pragma unroll
  for (int j = 0; j < 4; ++j) {
    const int col = n0 + wc + j*16 + lrow;
    const float bv = hasb ? bias[col] : 0.f;
    #pragma unroll
    for (int i = 0; i < 4; ++i) {
      const int r0 = m0 + wr + i*16 + lquad*4;
      #pragma unroll
      for (int v = 0; v < 4; ++v) {
        float val = acc[i][j][v] + bv;
        if (dorelu) val = fmaxf(val, 0.f);
        const size_t off = (size_t)(r0 + v) * N + col;
        if (outB) outB[off] = f2b(val);
        else      outF[off] = val;
      }
    }
  }
}

// ---------------------------------------------------------------------------
// All layers' rel_emb f32 [6][257][64] -> bf16 relB_all [6][272][64]
// ---------------------------------------------------------------------------
__global__ __launch_bounds__(256) void cvt_rel_all(
    const float* __restrict__ rel, u16* __restrict__ relB)
{
  const int i = blockIdx.x*256 + threadIdx.x;
  if (i < 6*257*64) {
    const int l = i / 16448, rem = i % 16448;
    relB[l*17408 + rem] = f2b(rel[i]);
  }
}

// ---------------------------------------------------------------------------
// MFMA flash attention (R6 structure: LDS-staged K/V, P aliased onto Ks,
// 3 barriers/kt). Max-free softmax, l via ones-MFMA. XCD swizzle.
// LDS 54272 B -> 3 blocks/CU.
// ---------------------------------------------------------------------------
__global__ __launch_bounds__(256) void attn_mfma(
    const u16* __restrict__ qkv, const u16* __restrict__ vT,
    const u16* __restrict__ relB, u16* __restrict__ ctx)
{
  const int id = blockIdx.x;
  const int xcd = id & 7, g = (id >> 3) & 15, qt = id >> 7;
  const int bh = xcd*16 + g;
  const int b = bh >> 3, h = bh & 7;
  const int t = threadIdx.x, w = t >> 6, lane = t & 63;
  const int lr = lane & 15, quad = lane >> 4;

  __shared__ __align__(16) u16 Ks[64*72];   // K tile, then aliased as P tile
  __shared__ __align__(16) u16 Vs[64*72];
  __shared__ __align__(16) u16 Pr[64*280];  // proj table, wave-private rows

  const size_t token0 = (size_t)b*512 + qt*64;

  short8 af0, af1;
  {
    const u16* qp = qkv + (token0 + w*16 + lr)*1536 + h*64 + quad*8;
    af0 = *(const short8*)(qp);
    af1 = *(const short8*)(qp + 32);
  }

  // Pr[q][j] = Q[q] . relB[j]
  #pragma unroll 4
  for (int nt = 0; nt < 17; ++nt) {
    const u16* rp = relB + (nt*16 + lr)*64 + quad*8;
    short8 rb0 = *(const short8*)(rp);
    short8 rb1 = *(const short8*)(rp + 32);
    floatx4 c = {0.f,0.f,0.f,0.f};
    c = __builtin_amdgcn_mfma_f32_16x16x32_bf16(af0, rb0, c, 0, 0, 0);
    c = __builtin_amdgcn_mfma_f32_16x16x32_bf16(af1, rb1, c, 0, 0, 0);
    #pragma unroll
    for (int r = 0; r < 4; ++r)
      Pr[(w*16 + quad*4 + r)*280 + nt*16 + lr] = f2b(c[r]);
  }

  floatx4 oacc[4];
  floatx4 lacc = {0.f,0.f,0.f,0.f};
  #pragma unroll
  for (int n = 0; n < 4; ++n) { floatx4 zz = {0.f,0.f,0.f,0.f}; oacc[n] = zz; }

  short8 ones;
  #pragma unroll
  for (int i = 0; i < 8; ++i) ones[i] = (short)0x3F80;  // bf16 1.0

  const int srow = t >> 2, scol = (t & 3) * 16;
  const u16* kbase = qkv + (size_t)b*512*1536 + 512 + h*64;
  const u16* vbase = vT + (size_t)(b*8 + h)*64*512;
  const int qg0 = qt*64 + w*16 + quad*4;

  for (int kt = 0; kt < 8; ++kt) {
    __syncthreads();  // prev iter's P/V reads done before overwrite
    {
      const u16* kp = kbase + (size_t)(kt*64 + srow)*1536 + scol;
      uint4 k0 = *(const uint4*)kp;
      uint4 k1 = *(const uint4*)(kp + 8);
      const u16* vp = vbase + (size_t)srow*512 + kt*64 + scol;
      uint4 v0 = *(const uint4*)vp;
      uint4 v1 = *(const uint4*)(vp + 8);
      *(uint4*)&Ks[srow*72 + scol]     = k0;
      *(uint4*)&Ks[srow*72 + scol + 8] = k1;
      *(uint4*)&Vs[srow*72 + scol]     = v0;
      *(uint4*)&Vs[srow*72 + scol + 8] = v1;
    }
    __syncthreads();

    // S = Q . K^T
    floatx4 s4[4];
    #pragma unroll
    for (int nt = 0; nt < 4; ++nt) {
      short8 kb0 = *(const short8*)&Ks[(nt*16 + lr)*72 + quad*8];
      short8 kb1 = *(const short8*)&Ks[(nt*16 + lr)*72 + 32 + quad*8];
      floatx4 c = {0.f,0.f,0.f,0.f};
      c = __builtin_amdgcn_mfma_f32_16x16x32_bf16(af0, kb0, c, 0, 0, 0);
      c = __builtin_amdgcn_mfma_f32_16x16x32_bf16(af1, kb1, c, 0, 0, 0);
      s4[nt] = c;
    }
    __syncthreads();  // all waves done reading Ks before P overwrites it

    // P = exp(S/8 + bias); write into Ks region (own rows only)
    const int kpos = kt*64 + lr;
    #pragma unroll
    for (int r = 0; r < 4; ++r) {
      const int qg = qg0 + r;
      const int prrow = (w*16 + quad*4 + r)*280;
      const int psrow = (w*16 + quad*4 + r)*72;
      #pragma unroll
      for (int nt = 0; nt < 4; ++nt) {
        int dd = (kpos + nt*16) - qg;
        dd = dd < -128 ? -128 : (dd > 128 ? 128 : dd);
        const float sc = fmaf(s4[nt][r], 0.125f, b2f(Pr[prrow + dd + 128]));
        Ks[psrow + nt*16 + lr] = f2b(__expf(sc));
      }
    }

    // O += P . V ; l += P . 1
    short8 pf0 = *(const short8*)&Ks[(w*16 + lr)*72 + quad*8];
    short8 pf1 = *(const short8*)&Ks[(w*16 + lr)*72 + 32 + quad*8];
    lacc = __builtin_amdgcn_mfma_f32_16x16x32_bf16(pf0, ones, lacc, 0, 0, 0);
    lacc = __builtin_amdgcn_mfma_f32_16x16x32_bf16(pf1, ones, lacc, 0, 0, 0);
    #pragma unroll
    for (int nd = 0; nd < 4; ++nd) {
      short8 vb0 = *(const short8*)&Vs[(nd*16 + lr)*72 + quad*8];
      short8 vb1 = *(const short8*)&Vs[(nd*16 + lr)*72 + 32 + quad*8];
      oacc[nd] = __builtin_amdgcn_mfma_f32_16x16x32_bf16(pf0, vb0, oacc[nd], 0, 0, 0);
      oacc[nd] = __builtin_amdgcn_mfma_f32_16x16x32_bf16(pf1, vb1, oacc[nd], 0, 0, 0);
    }
  }

  #pragma unroll
  for (int r = 0; r < 4; ++r) {
    const float inv = 1.f / lacc[r];
    u16* cp = ctx + (token0 + w*16 + quad*4 + r)*512 + h*64 + lr;
    #pragma unroll
    for (int nd = 0; nd < 4; ++nd)
      cp[nd*16] = f2b(oacc[nd][r] * inv);
  }
}

// ---------------------------------------------------------------------------
// LayerNorm over D=512: h = LN(b2f(resB) (+ add0) (+ add1)) * g + b -> hb
// Residual stream kept in bf16 (in-place row update; row-local, no races).
// ---------------------------------------------------------------------------
__global__ __launch_bounds__(128) void ln_kernel(
    const u16* __restrict__ resB, const float* __restrict__ add0,
    const float* __restrict__ add1,
    const float* __restrict__ g, const float* __restrict__ be,
    u16* __restrict__ hb)
{
  const int row = blockIdx.x, t = threadIdx.x;
  const size_t base = (size_t)row * 512;
  const u32 r0 = *(const u32*)(resB + base + t*4);
  const u32 r1 = *(const u32*)(resB + base + t*4 + 2);
  float x0 = lo16(r0), x1 = hi16(r0), x2 = lo16(r1), x3 = hi16(r1);
  if (add0) {
    const float4 a = *(const float4*)(add0 + base + t*4);
    x0 += a.x; x1 += a.y; x2 += a.z; x3 += a.w;
  }
  if (add1) {
    const float4 a = *(const float4*)(add1 + base + t*4);
    x0 += a.x; x1 += a.y; x2 += a.z; x3 += a.w;
  }
  float s = x0 + x1 + x2 + x3;
  #pragma unroll
  for (int off = 32; off > 0; off >>= 1) s += __shfl_down(s, off);
  __shared__ float red[2];
  const int wv = t >> 6, ln = t & 63;
  if (ln == 0) red[wv] = s;
  __syncthreads();
  const float mean = (red[0] + red[1]) * (1.f/512.f);
  const float dx0 = x0-mean, dx1 = x1-mean, dx2 = x2-mean, dx3 = x3-mean;
  float vs = dx0*dx0 + dx1*dx1 + dx2*dx2 + dx3*dx3;
  __syncthreads();
  #pragma unroll
  for (int off = 32; off > 0; off >>= 1) vs += __shfl_down(vs, off);
  if (ln == 0) red[wv] = vs;
  __syncthreads();
  const float var = (red[0] + red[1]) * (1.f/512.f);
  const float inv = 1.f / sqrtf(var + 1e-5f);
  const float4 gv = *(const float4*)(g + t*4);
  const float4 bv = *(const float4*)(be + t*4);
  const float y0 = dx0*inv*gv.x + bv.x;
  const float y1 = dx1*inv*gv.y + bv.y;
  const float y2 = dx2*inv*gv.z + bv.z;
  const float y3 = dx3*inv*gv.w + bv.w;
  u32* hp = (u32*)(hb + base + t*4);
  hp[0] = pack2(y0, y1); hp[1] = pack2(y2, y3);
}

// ---------------------------------------------------------------------------
// out[row] = hd1[row][:] . p2_w + p2_b   (256-dot, one wave per row), f32 out
// ---------------------------------------------------------------------------
__global__ __launch_bounds__(256) void head2_kernel(
    const u16* __restrict__ hd1, const float* __restrict__ p2w,
    const float* __restrict__ p2b, float* __restrict__ out)
{
  const int wv = threadIdx.x >> 6, ln = threadIdx.x & 63;
  const int row = blockIdx.x * 4 + wv;
  const u16* hp = hd1 + (size_t)row * 256 + ln*4;
  const u32 h0 = *(const u32*)hp, h1 = *(const u32*)(hp + 2);
  const float4 w = *(const float4*)(p2w + ln*4);
  float acc = lo16(h0)*w.x + hi16(h0)*w.y + lo16(h1)*w.z + hi16(h1)*w.w;
  #pragma unroll
  for (int off = 1; off < 64; off <<= 1) acc += __shfl_xor(acc, off);
  if (ln == 0) out[row] = acc + p2b[0];
}

// ---------------------------------------------------------------------------
extern "C" void kernel_launch(void* const* d_in, const int* in_sizes, int n_in,
                              void* d_out, int out_size, void* d_ws, size_t ws_size,
                              hipStream_t stream) {
  (void)in_sizes; (void)n_in; (void)out_size; (void)ws_size;
  const float* X    = (const float*)d_in[0];
  const float* INW  = (const float*)d_in[1];
  const float* INB  = (const float*)d_in[2];
  const float* WQ   = (const float*)d_in[3];
  const float* WK   = (const float*)d_in[4];
  const float* WV   = (const float*)d_in[5];
  const float* WO   = (const float*)d_in[6];
  const float* BO   = (const float*)d_in[7];
  const float* REL  = (const float*)d_in[8];
  const float* W1   = (const float*)d_in[9];
  const float* B1   = (const float*)d_in[10];
  const float* W2   = (const float*)d_in[11];
  const float* B2   = (const float*)d_in[12];
  const float* LN1G = (const float*)d_in[13];
  const float* LN1B = (const float*)d_in[14];
  const float* LN2G = (const float*)d_in[15];
  const float* LN2B = (const float*)d_in[16];
  const float* ONG  = (const float*)d_in[17];
  const float* ONB  = (const float*)d_in[18];
  const float* P1W  = (const float*)d_in[19];
  const float* P1B  = (const float*)d_in[20];
  const float* P2W  = (const float*)d_in[21];
  const float* P2B  = (const float*)d_in[22];
  float* out = (float*)d_out;

  char* ws = (char*)d_ws;
  u16*   wT    = (u16*)(ws + OFF_WT);
  u16*   hB    = (u16*)(ws + OFF_HB);
  u16*   qkv   = (u16*)(ws + OFF_QKV);
  u16*   ctx   = (u16*)(ws + OFF_CTX);
  float* gout0 = (float*)(ws + OFF_GOUT);
  float* gout1 = (float*)(ws + OFF_QKV);   // alias: dead during Wo/FFN2
  u16*   ff    = (u16*)(ws + OFF_FF);
  u16*   hd1   = (u16*)(ws + OFF_HD1);
  u16*   vTb   = (u16*)(ws + OFF_VT);
  u16*   relBa = (u16*)(ws + OFF_RELB);

  transpose_all<<<4640, 256, 0, stream>>>(WQ, WK, WV, WO, W1, W2, P1W, wT);
  cvt_rel_all<<<386, 256, 0, stream>>>(REL, relBa);
  input_proj<<<NTOK, 128, 0, stream>>>(X, INW, INB, hB);

  for (int l = 0; l < NLAYER; ++l) {
    const u16* wTl = wT + (size_t)l * LSTRIDE;
    // QKV fused: [8192,512] @ [512,1536]; Q,K -> qkv bf16, V -> vT transposed
    gemm_bt<<<dim3(768,1), 256, 0, stream>>>(hB, wTl, nullptr, nullptr, nullptr, qkv, vTb,
                                             8192, 1536, 512, 512, 4);
    attn_mfma<<<1024, 256, 0, stream>>>(qkv, vTb, relBa + l*17408, ctx);
    // Wo + bo, split-K=2 -> f32 partials
    gemm_bt<<<dim3(256,2), 256, 0, stream>>>(ctx, wTl + 786432, BO + l*512,
                                             gout0, gout1, nullptr, nullptr,
                                             8192, 512, 512, 256, 1);
    ln_kernel<<<NTOK, 128, 0, stream>>>(hB, gout0, gout1, LN1G + l*512, LN1B + l*512, hB);
    // FFN1: relu(h @ w1 + b1) -> bf16  (overwrites vT scratch - dead)
    gemm_bt<<<dim3(1024,1), 256, 0, stream>>>(hB, wTl + 1048576, B1 + l*2048,
                                              nullptr, nullptr, ff, nullptr,
                                              8192, 2048, 512, 512, 3);
    // FFN2: ff @ w2 + b2, split-K=2 -> f32 partials
    gemm_bt<<<dim3(256,2), 256, 0, stream>>>(ff, wTl + 2097152, B2 + l*512,
                                             gout0, gout1, nullptr, nullptr,
                                             8192, 512, 2048, 1024, 1);
    ln_kernel<<<NTOK, 128, 0, stream>>>(hB, gout0, gout1, LN2G + l*512, LN2B + l*512, hB);
  }
  ln_kernel<<<NTOK, 128, 0, stream>>>(hB, nullptr, nullptr, ONG, ONB, hB);
  // head: relu(h @ p1_w + p1_b) -> bf16 [8192][256]
  gemm_bt<<<dim3(128,1), 256, 0, stream>>>(hB, wT + P1T_OFF, P1B,
                                           nullptr, nullptr, hd1, nullptr,
                                           8192, 256, 512, 512, 3);
  head2_kernel<<<2048, 256, 0, stream>>>(hd1, P2W, P2B, out);
}

// Round 10
// 1199.553 us; speedup vs baseline: 1.2092x; 1.0161x over previous
//
#include <hip/hip_runtime.h>

typedef unsigned short u16;
typedef unsigned int   u32;
typedef short   short8  __attribute__((ext_vector_type(8)));
typedef float   floatx4 __attribute__((ext_vector_type(4)));

#define NTOK 8192
#define SEQ  512
#define NLAYER 6

// ---- workspace layout (bytes) ----
#define OFF_WT   ((size_t)0)          // transposed weights (bf16), 19,005,440 u16
#define OFF_HB   ((size_t)38010880)   // h bf16   [8192][512] (residual stream)
#define OFF_QKV  ((size_t)46399488)   // qkv bf16 [8192][1536] (25.2 MB)
#define OFF_CTX  ((size_t)71565312)   // ctx bf16 [8192][512]
#define OFF_GOUT ((size_t)79953920)   // gout0 fp32 [8192][512]
#define OFF_FF   ((size_t)96731136)   // ff bf16  [8192][2048]  (33.5 MB)
#define OFF_HD1  ((size_t)130285568)  // head1 bf16 [8192][256] (4.2 MB)
// aliases:
//   gout1 (split-K partial, f32 [8192][512]) -> qkv region (dead during Wo/FFN2)
//   vT bf16 [128 bh][64][512] (8.4 MB) -> ff region (dead during attn)
//   relB_all bf16 [6][272][64] (209 KB) -> hd1 region (hd1 written only at end)
#define OFF_VT   OFF_FF
#define OFF_RELB OFF_HD1

#define LSTRIDE 3145728   // wT elems per layer: [QT;KT;VT](1536x512), WoT, w1T(2048x512), w2T(512x2048)
#define P1T_OFF 18874368  // p1T [256][512]

__device__ __forceinline__ float b2f(u16 v) { return __uint_as_float(((u32)v) << 16); }
__device__ __forceinline__ float lo16(u32 v) { return __uint_as_float(v << 16); }
__device__ __forceinline__ float hi16(u32 v) { return __uint_as_float(v & 0xffff0000u); }
__device__ __forceinline__ u16 f2b(float f) {
  u32 x = __float_as_uint(f);
  return (u16)((x + 0x7fffu + ((x >> 16) & 1u)) >> 16);
}
__device__ __forceinline__ u32 pack2(float a, float b) {
  return (u32)f2b(a) | ((u32)f2b(b) << 16);
}

typedef __attribute__((address_space(1))) void* gas_t;
typedef __attribute__((address_space(3))) void* las_t;

// ---------------------------------------------------------------------------
// Transpose all f32 weight matrices into wT (bf16 [N][K] for gemm_bt).
// ---------------------------------------------------------------------------
__global__ __launch_bounds__(256) void transpose_all(
    const float* __restrict__ Wq, const float* __restrict__ Wk,
    const float* __restrict__ Wv, const float* __restrict__ Wo,
    const float* __restrict__ w1, const float* __restrict__ w2,
    const float* __restrict__ p1, u16* __restrict__ wT)
{
  __shared__ u16 tile[64][65];
  const int tb = blockIdx.x;
  const float* src; u16* dst; int R, C, tidx;
  if (tb < 4608) {
    const int l = tb / 768, r = tb % 768;
    const size_t lofs = (size_t)l * LSTRIDE;
    if (r < 256) {
      const int m = r >> 6; tidx = r & 63; R = 512; C = 512;
      const float* bases[4] = {Wq, Wk, Wv, Wo};
      src = bases[m] + (size_t)l * 262144;
      dst = wT + lofs + (size_t)m * 262144;
    } else if (r < 512) {
      tidx = r - 256; R = 512; C = 2048;
      src = w1 + (size_t)l * 1048576; dst = wT + lofs + 1048576;
    } else {
      tidx = r - 512; R = 2048; C = 512;
      src = w2 + (size_t)l * 1048576; dst = wT + lofs + 2097152;
    }
  } else {
    tidx = tb - 4608; R = 512; C = 256;
    src = p1; dst = wT + P1T_OFF;
  }
  const int tcn = C >> 6;
  const int tr = tidx / tcn, tc = tidx % tcn;
  const int th = threadIdx.x;
  {
    const int lr = th >> 2, cg = (th & 3) * 16;
    const float* sp = src + (size_t)(tr*64 + lr) * C + tc*64 + cg;
    float4 f0 = *(const float4*)(sp);
    float4 f1 = *(const float4*)(sp + 4);
    float4 f2 = *(const float4*)(sp + 8);
    float4 f3 = *(const float4*)(sp + 12);
    u16* tp = &tile[lr][cg];
    tp[0]=f2b(f0.x); tp[1]=f2b(f0.y); tp[2]=f2b(f0.z); tp[3]=f2b(f0.w);
    tp[4]=f2b(f1.x); tp[5]=f2b(f1.y); tp[6]=f2b(f1.z); tp[7]=f2b(f1.w);
    tp[8]=f2b(f2.x); tp[9]=f2b(f2.y); tp[10]=f2b(f2.z); tp[11]=f2b(f2.w);
    tp[12]=f2b(f3.x); tp[13]=f2b(f3.y); tp[14]=f2b(f3.z); tp[15]=f2b(f3.w);
  }
  __syncthreads();
  {
    const int oc = th >> 2, rg = (th & 3) * 16;
    u32 wds[8];
    #pragma unroll
    for (int i = 0; i < 8; ++i)
      wds[i] = (u32)tile[rg + 2*i][oc] | ((u32)tile[rg + 2*i + 1][oc] << 16);
    u16* dp = dst + (size_t)(tc*64 + oc) * R + tr*64 + rg;
    uint4 o0; o0.x=wds[0]; o0.y=wds[1]; o0.z=wds[2]; o0.w=wds[3];
    uint4 o1; o1.x=wds[4]; o1.y=wds[5]; o1.z=wds[6]; o1.w=wds[7];
    *(uint4*)dp = o0;
    *(uint4*)(dp + 8) = o1;
  }
}

// ---------------------------------------------------------------------------
// h = x @ in_w + in_b + sinusoidal_pe   (K=50, exact f32) -> bf16
// ---------------------------------------------------------------------------
__global__ __launch_bounds__(128) void input_proj(
    const float* __restrict__ x, const float* __restrict__ w, const float* __restrict__ ib,
    u16* __restrict__ hb)
{
  const int row = blockIdx.x, t = threadIdx.x;
  const int s = row & (SEQ - 1);
  __shared__ float xs[50];
  if (t < 50) xs[t] = x[row*50 + t];
  __syncthreads();
  #pragma unroll
  for (int rep = 0; rep < 4; ++rep) {
    const int d = rep*128 + t;
    float acc = ib[d];
    #pragma unroll
    for (int i = 0; i < 50; ++i) acc += xs[i] * w[i*512 + d];
    const int ii = d >> 1;
    const float dv = __expf((float)(2*ii) * -0.017988946f); // -ln(10000)/512
    const float ang = (float)s * dv;
    const float pe = (d & 1) ? cosf(ang) : sinf(ang);
    hb[(size_t)row*512 + d] = f2b(acc + pe);
  }
}

// ---------------------------------------------------------------------------
// C[M][N] = A[M][K] @ Bt[N][K]^T over k in [z*kLen, (z+1)*kLen)
// BK=64, XCD swizzle on bm. OPERAND-SWAPPED MFMA: mfma(bf, af) gives each
// lane 4 COLUMN-consecutive C values at a fixed row -> vectorized epilogue
// (uint2 for bf16, float4 for f32) instead of 64 scalar stores.
// z = blockIdx.y. z==0 gets +bias; relu per flags bit1.
// flags bit2: blocks with n0>=1024 write V directly in vT-transposed layout.
// ---------------------------------------------------------------------------
__global__ __launch_bounds__(256) void gemm_bt(
    const u16* __restrict__ A, const u16* __restrict__ Bt,
    const float* __restrict__ bias,
    float* __restrict__ outF0, float* __restrict__ outF1, u16* __restrict__ outB,
    u16* __restrict__ vTout,
    const int M, const int N, const int K, const int kLen, const int flags)
{
  __shared__ __align__(16) u16 As[2*128*32];
  __shared__ __align__(16) u16 Bs[2*128*32];
  const int id = blockIdx.x;
  const int xcd = id & 7, rest = id >> 3;
  const int bm = (rest & 7) * 8 + xcd;
  const int bn = rest >> 3;
  const int z = blockIdx.y;
  const int kOff = z * kLen;
  const int m0 = bm << 7, n0 = bn << 7;
  const int tid = threadIdx.x;
  const int wave = tid >> 6, lane = tid & 63;
  const int wr = (wave >> 1) << 6, wc = (wave & 1) << 6;
  const int lrow = lane & 15, lquad = lane >> 4;

  floatx4 acc[4][4];
  #pragma unroll
  for (int i = 0; i < 4; ++i)
    #pragma unroll
    for (int j = 0; j < 4; ++j) { floatx4 zz = {0.f,0.f,0.f,0.f}; acc[i][j] = zz; }

  const u16* a0p = A  + (size_t)m0 * K + kOff;
  const u16* b0p = Bt + (size_t)n0 * K + kOff;
  const int c0 = tid, c1 = 256 + tid;
  const int ar0 = c0 >> 2, as0 = (c0 & 3) * 8;
  const int ar1 = c1 >> 2, as1 = (c1 & 3) * 8;

  for (int k0 = 0; k0 < kLen; k0 += 64) {
    #pragma unroll
    for (int hh = 0; hh < 2; ++hh) {
      const int kk = k0 + hh*32;
      __builtin_amdgcn_global_load_lds((gas_t)(a0p + (size_t)ar0*K + kk + as0), (las_t)(&As[hh*4096 + c0*8]), 16, 0, 0);
      __builtin_amdgcn_global_load_lds((gas_t)(a0p + (size_t)ar1*K + kk + as1), (las_t)(&As[hh*4096 + c1*8]), 16, 0, 0);
      __builtin_amdgcn_global_load_lds((gas_t)(b0p + (size_t)ar0*K + kk + as0), (las_t)(&Bs[hh*4096 + c0*8]), 16, 0, 0);
      __builtin_amdgcn_global_load_lds((gas_t)(b0p + (size_t)ar1*K + kk + as1), (las_t)(&Bs[hh*4096 + c1*8]), 16, 0, 0);
    }
    __syncthreads();
    #pragma unroll
    for (int hh = 0; hh < 2; ++hh) {
      short8 af[4], bf[4];
      #pragma unroll
      for (int i = 0; i < 4; ++i) af[i] = *(const short8*)&As[hh*4096 + (wr + i*16 + lrow)*32 + lquad*8];
      #pragma unroll
      for (int j = 0; j < 4; ++j) bf[j] = *(const short8*)&Bs[hh*4096 + (wc + j*16 + lrow)*32 + lquad*8];
      #pragma unroll
      for (int i = 0; i < 4; ++i)
        #pragma unroll
        for (int j = 0; j < 4; ++j)
          acc[i][j] = __builtin_amdgcn_mfma_f32_16x16x32_bf16(bf[j], af[i], acc[i][j], 0, 0, 0);
    }
    __syncthreads();
  }

  // Swapped layout: lane owns row = m0+wr+i*16+lrow (fixed),
  //                 cols = n0+wc+j*16+lquad*4 + v (v=0..3 consecutive)
  if ((flags & 4) && n0 >= 1024) {
    // V block of QKV: write into vT[(b*8+h)*64+d][s] (bf16), scalar stores
    #pragma unroll
    for (int i = 0; i < 4; ++i) {
      const int row = m0 + wr + i*16 + lrow;
      const int bb = row >> 9, s = row & 511;
      #pragma unroll
      for (int j = 0; j < 4; ++j) {
        const int cm0 = (n0 - 1024) + wc + j*16 + lquad*4;
        #pragma unroll
        for (int v = 0; v < 4; ++v) {
          const int cm = cm0 + v;
          const int hh = cm >> 6, d = cm & 63;
          vTout[((size_t)(bb*8 + hh)*64 + d)*512 + s] = f2b(acc[i][j][v]);
        }
      }
    }
    return;
  }

  float* outF = (z == 0) ? outF0 : outF1;
  const bool hasb = ((flags & 1) != 0) && (z == 0);
  const bool dorelu = (flags & 2) != 0;
  #pragma unroll
  for (int i = 0; i < 4; ++i) {
    const int row = m0 + wr + i*16 + lrow;
    #pragma unroll
    for (int j = 0; j < 4; ++j) {
      const int colbase = n0 + wc + j*16 + lquad*4;
      float4 bv4 = make_float4(0.f, 0.f, 0.f, 0.f);
      if (hasb) bv4 = *(const float4*)(bias + colbase);
      float v0 = acc[i][j][0] + bv4.x;
      float v1 = acc[i][j][1] + bv4.y;
      float v2 = acc[i][j][2] + bv4.z;
      float v3 = acc[i][j][3] + bv4.w;
      if (dorelu) {
        v0 = fmaxf(v0, 0.f); v1 = fmaxf(v1, 0.f);
        v2 = fmaxf(v2, 0.f); v3 = fmaxf(v3, 0.f);
      }
      const size_t off = (size_t)row * N + colbase;
      if (outB) {
        uint2 o; o.x = pack2(v0, v1); o.y = pack2(v2, v3);
        *(uint2*)(outB + off) = o;
      } else {
        *(float4*)(outF + off) = make_float4(v0, v1, v2, v3);
      }
    }
  }
}

// ---------------------------------------------------------------------------
// All layers' rel_emb f32 [6][257][64] -> bf16 relB_all [6][272][64]
// ---------------------------------------------------------------------------
__global__ __launch_bounds__(256) void cvt_rel_all(
    const float* __restrict__ rel, u16* __restrict__ relB)
{
  const int i = blockIdx.x*256 + threadIdx.x;
  if (i < 6*257*64) {
    const int l = i / 16448, rem = i % 16448;
    relB[l*17408 + rem] = f2b(rel[i]);
  }
}

// ---------------------------------------------------------------------------
// MFMA flash attention (R6 structure). PV + ones-MFMA operand-swapped so the
// ctx epilogue is 4 uint2 stores instead of 16 scalar u16.
// LDS 54272 B -> 3 blocks/CU. XCD swizzle on (b,h).
// ---------------------------------------------------------------------------
__global__ __launch_bounds__(256) void attn_mfma(
    const u16* __restrict__ qkv, const u16* __restrict__ vT,
    const u16* __restrict__ relB, u16* __restrict__ ctx)
{
  const int id = blockIdx.x;
  const int xcd = id & 7, g = (id >> 3) & 15, qt = id >> 7;
  const int bh = xcd*16 + g;
  const int b = bh >> 3, h = bh & 7;
  const int t = threadIdx.x, w = t >> 6, lane = t & 63;
  const int lr = lane & 15, quad = lane >> 4;

  __shared__ __align__(16) u16 Ks[64*72];   // K tile, then aliased as P tile
  __shared__ __align__(16) u16 Vs[64*72];
  __shared__ __align__(16) u16 Pr[64*280];  // proj table, wave-private rows

  const size_t token0 = (size_t)b*512 + qt*64;

  short8 af0, af1;
  {
    const u16* qp = qkv + (token0 + w*16 + lr)*1536 + h*64 + quad*8;
    af0 = *(const short8*)(qp);
    af1 = *(const short8*)(qp + 32);
  }

  // Pr[q][j] = Q[q] . relB[j]
  #pragma unroll 4
  for (int nt = 0; nt < 17; ++nt) {
    const u16* rp = relB + (nt*16 + lr)*64 + quad*8;
    short8 rb0 = *(const short8*)(rp);
    short8 rb1 = *(const short8*)(rp + 32);
    floatx4 c = {0.f,0.f,0.f,0.f};
    c = __builtin_amdgcn_mfma_f32_16x16x32_bf16(af0, rb0, c, 0, 0, 0);
    c = __builtin_amdgcn_mfma_f32_16x16x32_bf16(af1, rb1, c, 0, 0, 0);
    #pragma unroll
    for (int r = 0; r < 4; ++r)
      Pr[(w*16 + quad*4 + r)*280 + nt*16 + lr] = f2b(c[r]);
  }

  floatx4 oacc[4];
  floatx4 lacc = {0.f,0.f,0.f,0.f};
  #pragma unroll
  for (int n = 0; n < 4; ++n) { floatx4 zz = {0.f,0.f,0.f,0.f}; oacc[n] = zz; }

  short8 ones;
  #pragma unroll
  for (int i = 0; i < 8; ++i) ones[i] = (short)0x3F80;  // bf16 1.0

  const int srow = t >> 2, scol = (t & 3) * 16;
  const u16* kbase = qkv + (size_t)b*512*1536 + 512 + h*64;
  const u16* vbase = vT + (size_t)(b*8 + h)*64*512;
  const int qg0 = qt*64 + w*16 + quad*4;

  for (int kt = 0; kt < 8; ++kt) {
    __syncthreads();  // prev iter's P/V reads done before overwrite
    {
      const u16* kp = kbase + (size_t)(kt*64 + srow)*1536 + scol;
      uint4 k0 = *(const uint4*)kp;
      uint4 k1 = *(const uint4*)(kp + 8);
      const u16* vp = vbase + (size_t)srow*512 + kt*64 + scol;
      uint4 v0 = *(const uint4*)vp;
      uint4 v1 = *(const uint4*)(vp + 8);
      *(uint4*)&Ks[srow*72 + scol]     = k0;
      *(uint4*)&Ks[srow*72 + scol + 8] = k1;
      *(uint4*)&Vs[srow*72 + scol]     = v0;
      *(uint4*)&Vs[srow*72 + scol + 8] = v1;
    }
    __syncthreads();

    // S = Q . K^T  (C layout: col=lr -> k, row=quad*4+r -> q)
    floatx4 s4[4];
    #pragma unroll
    for (int nt = 0; nt < 4; ++nt) {
      short8 kb0 = *(const short8*)&Ks[(nt*16 + lr)*72 + quad*8];
      short8 kb1 = *(const short8*)&Ks[(nt*16 + lr)*72 + 32 + quad*8];
      floatx4 c = {0.f,0.f,0.f,0.f};
      c = __builtin_amdgcn_mfma_f32_16x16x32_bf16(af0, kb0, c, 0, 0, 0);
      c = __builtin_amdgcn_mfma_f32_16x16x32_bf16(af1, kb1, c, 0, 0, 0);
      s4[nt] = c;
    }
    __syncthreads();  // all waves done reading Ks before P overwrites it

    // P = exp(S/8 + bias); write into Ks region (own rows only)
    const int kpos = kt*64 + lr;
    #pragma unroll
    for (int r = 0; r < 4; ++r) {
      const int qg = qg0 + r;
      const int prrow = (w*16 + quad*4 + r)*280;
      const int psrow = (w*16 + quad*4 + r)*72;
      #pragma unroll
      for (int nt = 0; nt < 4; ++nt) {
        int dd = (kpos + nt*16) - qg;
        dd = dd < -128 ? -128 : (dd > 128 ? 128 : dd);
        const float sc = fmaf(s4[nt][r], 0.125f, b2f(Pr[prrow + dd + 128]));
        Ks[psrow + nt*16 + lr] = f2b(__expf(sc));
      }
    }

    // O += V^T-frag x P  (swapped: lane gets fixed q=lr, 4 consecutive d)
    short8 pf0 = *(const short8*)&Ks[(w*16 + lr)*72 + quad*8];
    short8 pf1 = *(const short8*)&Ks[(w*16 + lr)*72 + 32 + quad*8];
    lacc = __builtin_amdgcn_mfma_f32_16x16x32_bf16(ones, pf0, lacc, 0, 0, 0);
    lacc = __builtin_amdgcn_mfma_f32_16x16x32_bf16(ones, pf1, lacc, 0, 0, 0);
    #pragma unroll
    for (int nd = 0; nd < 4; ++nd) {
      short8 vb0 = *(const short8*)&Vs[(nd*16 + lr)*72 + quad*8];
      short8 vb1 = *(const short8*)&Vs[(nd*16 + lr)*72 + 32 + quad*8];
      oacc[nd] = __builtin_amdgcn_mfma_f32_16x16x32_bf16(vb0, pf0, oacc[nd], 0, 0, 0);
      oacc[nd] = __builtin_amdgcn_mfma_f32_16x16x32_bf16(vb1, pf1, oacc[nd], 0, 0, 0);
    }
  }

  // epilogue: q = lr (fixed per lane); lacc all-regs = row-sum of q
  {
    const float inv = 1.f / lacc[0];
    u16* cp = ctx + (token0 + w*16 + lr)*512 + h*64;
    #pragma unroll
    for (int nd = 0; nd < 4; ++nd) {
      const int d = nd*16 + quad*4;
      uint2 o;
      o.x = pack2(oacc[nd][0]*inv, oacc[nd][1]*inv);
      o.y = pack2(oacc[nd][2]*inv, oacc[nd][3]*inv);
      *(uint2*)(cp + d) = o;
    }
  }
}

// ---------------------------------------------------------------------------
// LayerNorm over D=512: h = LN(b2f(resB) (+ add0) (+ add1)) * g + b -> hb
// ---------------------------------------------------------------------------
__global__ __launch_bounds__(128) void ln_kernel(
    const u16* __restrict__ resB, const float* __restrict__ add0,
    const float* __restrict__ add1,
    const float* __restrict__ g, const float* __restrict__ be,
    u16* __restrict__ hb)
{
  const int row = blockIdx.x, t = threadIdx.x;
  const size_t base = (size_t)row * 512;
  const u32 r0 = *(const u32*)(resB + base + t*4);
  const u32 r1 = *(const u32*)(resB + base + t*4 + 2);
  float x0 = lo16(r0), x1 = hi16(r0), x2 = lo16(r1), x3 = hi16(r1);
  if (add0) {
    const float4 a = *(const float4*)(add0 + base + t*4);
    x0 += a.x; x1 += a.y; x2 += a.z; x3 += a.w;
  }
  if (add1) {
    const float4 a = *(const float4*)(add1 + base + t*4);
    x0 += a.x; x1 += a.y; x2 += a.z; x3 += a.w;
  }
  float s = x0 + x1 + x2 + x3;
  #pragma unroll
  for (int off = 32; off > 0; off >>= 1) s += __shfl_down(s, off);
  __shared__ float red[2];
  const int wv = t >> 6, ln = t & 63;
  if (ln == 0) red[wv] = s;
  __syncthreads();
  const float mean = (red[0] + red[1]) * (1.f/512.f);
  const float dx0 = x0-mean, dx1 = x1-mean, dx2 = x2-mean, dx3 = x3-mean;
  float vs = dx0*dx0 + dx1*dx1 + dx2*dx2 + dx3*dx3;
  __syncthreads();
  #pragma unroll
  for (int off = 32; off > 0; off >>= 1) vs += __shfl_down(vs, off);
  if (ln == 0) red[wv] = vs;
  __syncthreads();
  const float var = (red[0] + red[1]) * (1.f/512.f);
  const float inv = 1.f / sqrtf(var + 1e-5f);
  const float4 gv = *(const float4*)(g + t*4);
  const float4 bv = *(const float4*)(be + t*4);
  const float y0 = dx0*inv*gv.x + bv.x;
  const float y1 = dx1*inv*gv.y + bv.y;
  const float y2 = dx2*inv*gv.z + bv.z;
  const float y3 = dx3*inv*gv.w + bv.w;
  u32* hp = (u32*)(hb + base + t*4);
  hp[0] = pack2(y0, y1); hp[1] = pack2(y2, y3);
}

// ---------------------------------------------------------------------------
// out[row] = hd1[row][:] . p2_w + p2_b   (256-dot, one wave per row), f32 out
// ---------------------------------------------------------------------------
__global__ __launch_bounds__(256) void head2_kernel(
    const u16* __restrict__ hd1, const float* __restrict__ p2w,
    const float* __restrict__ p2b, float* __restrict__ out)
{
  const int wv = threadIdx.x >> 6, ln = threadIdx.x & 63;
  const int row = blockIdx.x * 4 + wv;
  const u16* hp = hd1 + (size_t)row * 256 + ln*4;
  const u32 h0 = *(const u32*)hp, h1 = *(const u32*)(hp + 2);
  const float4 w = *(const float4*)(p2w + ln*4);
  float acc = lo16(h0)*w.x + hi16(h0)*w.y + lo16(h1)*w.z + hi16(h1)*w.w;
  #pragma unroll
  for (int off = 1; off < 64; off <<= 1) acc += __shfl_xor(acc, off);
  if (ln == 0) out[row] = acc + p2b[0];
}

// ---------------------------------------------------------------------------
extern "C" void kernel_launch(void* const* d_in, const int* in_sizes, int n_in,
                              void* d_out, int out_size, void* d_ws, size_t ws_size,
                              hipStream_t stream) {
  (void)in_sizes; (void)n_in; (void)out_size; (void)ws_size;
  const float* X    = (const float*)d_in[0];
  const float* INW  = (const float*)d_in[1];
  const float* INB  = (const float*)d_in[2];
  const float* WQ   = (const float*)d_in[3];
  const float* WK   = (const float*)d_in[4];
  const float* WV   = (const float*)d_in[5];
  const float* WO   = (const float*)d_in[6];
  const float* BO   = (const float*)d_in[7];
  const float* REL  = (const float*)d_in[8];
  const float* W1   = (const float*)d_in[9];
  const float* B1   = (const float*)d_in[10];
  const float* W2   = (const float*)d_in[11];
  const float* B2   = (const float*)d_in[12];
  const float* LN1G = (const float*)d_in[13];
  const float* LN1B = (const float*)d_in[14];
  const float* LN2G = (const float*)d_in[15];
  const float* LN2B = (const float*)d_in[16];
  const float* ONG  = (const float*)d_in[17];
  const float* ONB  = (const float*)d_in[18];
  const float* P1W  = (const float*)d_in[19];
  const float* P1B  = (const float*)d_in[20];
  const float* P2W  = (const float*)d_in[21];
  const float* P2B  = (const float*)d_in[22];
  float* out = (float*)d_out;

  char* ws = (char*)d_ws;
  u16*   wT    = (u16*)(ws + OFF_WT);
  u16*   hB    = (u16*)(ws + OFF_HB);
  u16*   qkv   = (u16*)(ws + OFF_QKV);
  u16*   ctx   = (u16*)(ws + OFF_CTX);
  float* gout0 = (float*)(ws + OFF_GOUT);
  float* gout1 = (float*)(ws + OFF_QKV);   // alias: dead during Wo/FFN2
  u16*   ff    = (u16*)(ws + OFF_FF);
  u16*   hd1   = (u16*)(ws + OFF_HD1);
  u16*   vTb   = (u16*)(ws + OFF_VT);
  u16*   relBa = (u16*)(ws + OFF_RELB);

  transpose_all<<<4640, 256, 0, stream>>>(WQ, WK, WV, WO, W1, W2, P1W, wT);
  cvt_rel_all<<<386, 256, 0, stream>>>(REL, relBa);
  input_proj<<<NTOK, 128, 0, stream>>>(X, INW, INB, hB);

  for (int l = 0; l < NLAYER; ++l) {
    const u16* wTl = wT + (size_t)l * LSTRIDE;
    // QKV fused: [8192,512] @ [512,1536]; Q,K -> qkv bf16, V -> vT transposed
    gemm_bt<<<dim3(768,1), 256, 0, stream>>>(hB, wTl, nullptr, nullptr, nullptr, qkv, vTb,
                                             8192, 1536, 512, 512, 4);
    attn_mfma<<<1024, 256, 0, stream>>>(qkv, vTb, relBa + l*17408, ctx);
    // Wo + bo, split-K=2 -> f32 partials
    gemm_bt<<<dim3(256,2), 256, 0, stream>>>(ctx, wTl + 786432, BO + l*512,
                                             gout0, gout1, nullptr, nullptr,
                                             8192, 512, 512, 256, 1);
    ln_kernel<<<NTOK, 128, 0, stream>>>(hB, gout0, gout1, LN1G + l*512, LN1B + l*512, hB);
    // FFN1: relu(h @ w1 + b1) -> bf16  (overwrites vT scratch - dead)
    gemm_bt<<<dim3(1024,1), 256, 0, stream>>>(hB, wTl + 1048576, B1 + l*2048,
                                              nullptr, nullptr, ff, nullptr,
                                              8192, 2048, 512, 512, 3);
    // FFN2: ff @ w2 + b2, split-K=2 -> f32 partials
    gemm_bt<<<dim3(256,2), 256, 0, stream>>>(ff, wTl + 2097152, B2 + l*512,
                                             gout0, gout1, nullptr, nullptr,
                                             8192, 512, 2048, 1024, 1);
    ln_kernel<<<NTOK, 128, 0, stream>>>(hB, gout0, gout1, LN2G + l*512, LN2B + l*512, hB);
  }
  ln_kernel<<<NTOK, 128, 0, stream>>>(hB, nullptr, nullptr, ONG, ONB, hB);
  // head: relu(h @ p1_w + p1_b) -> bf16 [8192][256]
  gemm_bt<<<dim3(128,1), 256, 0, stream>>>(hB, wT + P1T_OFF, P1B,
                                           nullptr, nullptr, hd1, nullptr,
                                           8192, 256, 512, 512, 3);
  head2_kernel<<<2048, 256, 0, stream>>>(hd1, P2W, P2B, out);
}